// Round 1
// baseline (190.271 us; speedup 1.0000x reference)
//
#include <hip/hip_runtime.h>
#include <math.h>

// Problem constants (B=2, N=256, F=64, H=64, HEADS=4, C=256)
#define EPSV 1e-5f
#define INFV 1e5f

__device__ __forceinline__ float silu_f(float v) { return v / (1.0f + __expf(-v)); }

// Block-wide reduction of a float4 across 256 threads (4 waves of 64).
// op=0: sum, op=1: max. sc must be __shared__ float4[4].
__device__ __forceinline__ float4 br4(float4 v, int op, float4* sc) {
  const int tid = threadIdx.x;
#pragma unroll
  for (int off = 32; off >= 1; off >>= 1) {
    float ox = __shfl_xor(v.x, off);
    float oy = __shfl_xor(v.y, off);
    float oz = __shfl_xor(v.z, off);
    float ow = __shfl_xor(v.w, off);
    if (op) { v.x = fmaxf(v.x, ox); v.y = fmaxf(v.y, oy); v.z = fmaxf(v.z, oz); v.w = fmaxf(v.w, ow); }
    else    { v.x += ox; v.y += oy; v.z += oz; v.w += ow; }
  }
  if ((tid & 63) == 0) sc[tid >> 6] = v;
  __syncthreads();
  float4 r0 = sc[0], r1 = sc[1], r2 = sc[2], r3 = sc[3];
  if (op) {
    v.x = fmaxf(fmaxf(r0.x, r1.x), fmaxf(r2.x, r3.x));
    v.y = fmaxf(fmaxf(r0.y, r1.y), fmaxf(r2.y, r3.y));
    v.z = fmaxf(fmaxf(r0.z, r1.z), fmaxf(r2.z, r3.z));
    v.w = fmaxf(fmaxf(r0.w, r1.w), fmaxf(r2.w, r3.w));
  } else {
    v.x = r0.x + r1.x + r2.x + r3.x;
    v.y = r0.y + r1.y + r2.y + r3.y;
    v.z = r0.z + r1.z + r2.z + r3.z;
    v.w = r0.w + r1.w + r2.w + r3.w;
  }
  __syncthreads();
  return v;
}

// K1: per-node precompute A = h @ W1[h_j part], Bm = h @ W1[h_i part]
__global__ void k_pre(const float* __restrict__ h, const float* __restrict__ ew1,
                      float* __restrict__ A, float* __restrict__ Bm) {
  __shared__ __align__(16) float hl[64];
  const int bn = blockIdx.x;     // 0..511 = b*256+n
  const int kk = threadIdx.x;    // 0..63
  hl[kk] = h[(size_t)bn * 64 + kk];
  __syncthreads();
  float a = 0.f, bb = 0.f;
#pragma unroll 8
  for (int f = 0; f < 64; ++f) {
    float hv = hl[f];
    a  += hv * ew1[f * 64 + kk];
    bb += hv * ew1[(64 + f) * 64 + kk];
  }
  A[(size_t)bn * 64 + kk]  = a;
  Bm[(size_t)bn * 64 + kk] = bb;
}

// K2: per (b,i) block, thread per j. Edge MLP, attentions, delta_v.
__global__ __launch_bounds__(256) void k_edge(
    const float* __restrict__ x, const float* __restrict__ ew1,
    const float* __restrict__ eb1, const float* __restrict__ ew2,
    const float* __restrict__ eb2,
    const float* __restrict__ semw, const float* __restrict__ semb,
    const float* __restrict__ vmix, const float* __restrict__ lgam,
    const float* __restrict__ A, const float* __restrict__ Bm,
    float* __restrict__ HE, float* __restrict__ ATT, float* __restrict__ DV) {
  __shared__ float4 sc[4];
  const int bi = blockIdx.x;          // b*256 + i
  const int i  = bi & 255;
  const int j  = threadIdx.x;         // 0..255
  const int bj = (bi & ~255) | j;     // b*256 + j

  // geometry (xi reads are wave-uniform -> scalar loads)
  const float xi0 = x[bi * 3 + 0], xi1 = x[bi * 3 + 1], xi2 = x[bi * 3 + 2];
  const float dx = x[bj * 3 + 0] - xi0;
  const float dy = x[bj * 3 + 1] - xi1;
  const float dz = x[bj * 3 + 2] - xi2;
  const float dn = sqrtf(dx * dx + dy * dy + dz * dz + EPSV);
  const float invn = 1.0f / (dn + EPSV);
  const float ux = dx * invn, uy = dy * invn, uz = dz * invn;

  const float* __restrict__ Arow  = A + (size_t)bj * 64;
  const float* __restrict__ bmrow = Bm + (size_t)bi * 64;   // uniform
  const float* __restrict__ w1d   = ew1 + 128 * 64;         // distance row of edge_w1

  // layer-2 accumulators (must stay fully register-resident: all index sites unrolled)
  float acc[64];
#pragma unroll
  for (int k = 0; k < 64; ++k) acc[k] = eb2[k];

  // fused layer1 (silu) + layer2 accumulate. ew2 indices are wave-uniform -> s_load.
  for (int m0 = 0; m0 < 64; m0 += 4) {
    float4 av = *reinterpret_cast<const float4*>(Arow + m0);
    float tv0 = silu_f(av.x + bmrow[m0 + 0] + dn * w1d[m0 + 0] + eb1[m0 + 0]);
    float tv1 = silu_f(av.y + bmrow[m0 + 1] + dn * w1d[m0 + 1] + eb1[m0 + 1]);
    float tv2 = silu_f(av.z + bmrow[m0 + 2] + dn * w1d[m0 + 2] + eb1[m0 + 2]);
    float tv3 = silu_f(av.w + bmrow[m0 + 3] + dn * w1d[m0 + 3] + eb1[m0 + 3]);
#pragma unroll
    for (int k0 = 0; k0 < 64; k0 += 4) {
      float4 w0 = *reinterpret_cast<const float4*>(ew2 + (m0 + 0) * 64 + k0);
      float4 w1 = *reinterpret_cast<const float4*>(ew2 + (m0 + 1) * 64 + k0);
      float4 w2 = *reinterpret_cast<const float4*>(ew2 + (m0 + 2) * 64 + k0);
      float4 w3 = *reinterpret_cast<const float4*>(ew2 + (m0 + 3) * 64 + k0);
      acc[k0 + 0] += tv0 * w0.x + tv1 * w1.x + tv2 * w2.x + tv3 * w3.x;
      acc[k0 + 1] += tv0 * w0.y + tv1 * w1.y + tv2 * w2.y + tv3 * w3.y;
      acc[k0 + 2] += tv0 * w0.z + tv1 * w1.z + tv2 * w2.z + tv3 * w3.z;
      acc[k0 + 3] += tv0 * w0.w + tv1 * w1.w + tv2 * w2.w + tv3 * w3.w;
    }
  }
#pragma unroll
  for (int k = 0; k < 64; ++k) acc[k] = silu_f(acc[k]);   // acc now holds h_e row

  // store HE row (needed by K3)
  float* __restrict__ herow = HE + ((size_t)bi * 256 + j) * 64;
#pragma unroll
  for (int k0 = 0; k0 < 64; k0 += 4) {
    *reinterpret_cast<float4*>(herow + k0) =
        make_float4(acc[k0], acc[k0 + 1], acc[k0 + 2], acc[k0 + 3]);
  }

  // semantic logits
  float4 sl = *reinterpret_cast<const float4*>(semb);
#pragma unroll
  for (int k = 0; k < 64; ++k) {
    float4 sw = *reinterpret_cast<const float4*>(semw + k * 4);
    sl.x += acc[k] * sw.x; sl.y += acc[k] * sw.y;
    sl.z += acc[k] * sw.z; sl.w += acc[k] * sw.w;
  }
  const float diag = (j == i) ? INFV : 0.0f;
  sl.x = ((sl.x > 0.f) ? sl.x : 0.2f * sl.x) - diag;
  sl.y = ((sl.y > 0.f) ? sl.y : 0.2f * sl.y) - diag;
  sl.z = ((sl.z > 0.f) ? sl.z : 0.2f * sl.z) - diag;
  sl.w = ((sl.w > 0.f) ? sl.w : 0.2f * sl.w) - diag;

  // euclidean logits: -(dn + INF*eye) * exp(log_gamma)
  float4 lg = *reinterpret_cast<const float4*>(lgam);
  const float dni = dn + diag;
  float4 dl = make_float4(-dni * __expf(lg.x), -dni * __expf(lg.y),
                          -dni * __expf(lg.z), -dni * __expf(lg.w));

  // softmax over j: euclid
  float4 M = br4(dl, 1, sc);
  float4 e = make_float4(__expf(dl.x - M.x), __expf(dl.y - M.y),
                         __expf(dl.z - M.z), __expf(dl.w - M.w));
  float4 S = br4(e, 0, sc);
  float4 ea = make_float4(e.x / S.x, e.y / S.y, e.z / S.z, e.w / S.w);

  // softmax over j: semantic
  M = br4(sl, 1, sc);
  e = make_float4(__expf(sl.x - M.x), __expf(sl.y - M.y),
                  __expf(sl.z - M.z), __expf(sl.w - M.w));
  S = br4(e, 0, sc);
  float4 sa = make_float4(e.x / S.x, e.y / S.y, e.z / S.z, e.w / S.w);

  // softmax over j of the product
  float4 p = make_float4(ea.x * sa.x, ea.y * sa.y, ea.z * sa.z, ea.w * sa.w);
  M = br4(p, 1, sc);
  e = make_float4(__expf(p.x - M.x), __expf(p.y - M.y),
                  __expf(p.z - M.z), __expf(p.w - M.w));
  S = br4(e, 0, sc);
  float4 catt = make_float4(e.x / S.x, e.y / S.y, e.z / S.z, e.w / S.w);

  *reinterpret_cast<float4*>(ATT + ((size_t)bi * 256 + j) * 4) = catt;

  // s_j = sum_c he_att[j,c] * vmix[c];  delta_v = (1/N) sum_j s_j * unit_j
  float s = 0.f;
#pragma unroll
  for (int k = 0; k < 64; ++k) {
    float4 vm = *reinterpret_cast<const float4*>(vmix + k * 4);
    s += acc[k] * (catt.x * vm.x + catt.y * vm.y + catt.z * vm.z + catt.w * vm.w);
  }
  float4 dv = br4(make_float4(s * ux, s * uy, s * uz, 0.f), 0, sc);
  if (j == 0) {
    const float inv = 1.0f / 256.0f;
    DV[bi * 3 + 0] = dv.x * inv;
    DV[bi * 3 + 1] = dv.y * inv;
    DV[bi * 3 + 2] = dv.z * inv;
  }
}

// K3: per (b,i) block. comb_sum/h_agg GEMM-lite + post/node/vel MLPs + outputs.
__global__ __launch_bounds__(256) void k_comb(
    const float* __restrict__ h, const float* __restrict__ x, const float* __restrict__ v,
    const float* __restrict__ pw1, const float* __restrict__ pb1,
    const float* __restrict__ pw2, const float* __restrict__ pb2,
    const float* __restrict__ nw1, const float* __restrict__ nb1,
    const float* __restrict__ nw2, const float* __restrict__ nb2,
    const float* __restrict__ vw1, const float* __restrict__ vb1,
    const float* __restrict__ vw2,
    const float* __restrict__ HE, const float* __restrict__ ATT,
    const float* __restrict__ DV, float* __restrict__ out) {
  __shared__ __align__(16) float cat_l[256 * 4];
  __shared__ __align__(16) float unit_l[256 * 4];
  __shared__ __align__(16) float hec[64 * 68];        // 64-row HE chunk, padded
  __shared__ __align__(16) float part[4 * 64 * 16];   // per-strip partials
  __shared__ float cn_l[256];
  __shared__ float hag_l[256];
  __shared__ float m1[64];
  __shared__ float hcm[64];
  __shared__ float hnw[64];

  const int bi  = blockIdx.x;
  const int tid = threadIdx.x;

  // stage comb_att + unit vectors
  {
    const int j  = tid;
    const int bj = (bi & ~255) | j;
    *reinterpret_cast<float4*>(cat_l + j * 4) =
        *reinterpret_cast<const float4*>(ATT + ((size_t)bi * 256 + j) * 4);
    float xi0 = x[bi * 3 + 0], xi1 = x[bi * 3 + 1], xi2 = x[bi * 3 + 2];
    float dx = x[bj * 3 + 0] - xi0, dy = x[bj * 3 + 1] - xi1, dz = x[bj * 3 + 2] - xi2;
    float dn = sqrtf(dx * dx + dy * dy + dz * dz + EPSV);
    float invn = 1.0f / (dn + EPSV);
    *reinterpret_cast<float4*>(unit_l + j * 4) =
        make_float4(dx * invn, dy * invn, dz * invn, 0.f);
  }

  const int k = tid & 63;         // output channel k
  const int strip = tid >> 6;     // wave id = j-sub-strip
  float agg[4] = {0.f, 0.f, 0.f, 0.f};
  float ax[4] = {0.f, 0.f, 0.f, 0.f};
  float ay[4] = {0.f, 0.f, 0.f, 0.f};
  float az[4] = {0.f, 0.f, 0.f, 0.f};

  for (int ch = 0; ch < 4; ++ch) {
    __syncthreads();   // protect hec (prev chunk) + staging on first iter
    const float4* src = reinterpret_cast<const float4*>(HE + ((size_t)bi * 256 + ch * 64) * 64);
#pragma unroll
    for (int q = 0; q < 4; ++q) {
      int f = q * 256 + tid;                  // 0..1023 float4s
      int r = f >> 4, c4 = f & 15;
      *reinterpret_cast<float4*>(hec + r * 68 + c4 * 4) = src[f];
    }
    __syncthreads();
#pragma unroll 4
    for (int rr2 = 0; rr2 < 16; ++rr2) {
      int rr = strip * 16 + rr2;
      int j = ch * 64 + rr;
      float he = hec[rr * 68 + k];
      float4 ca = *reinterpret_cast<const float4*>(cat_l + j * 4);   // wave-uniform
      float4 u  = *reinterpret_cast<const float4*>(unit_l + j * 4);  // wave-uniform
      float w0 = he * ca.x, w1 = he * ca.y, w2 = he * ca.z, w3 = he * ca.w;
      agg[0] += w0; agg[1] += w1; agg[2] += w2; agg[3] += w3;
      ax[0] += w0 * u.x; ay[0] += w0 * u.y; az[0] += w0 * u.z;
      ax[1] += w1 * u.x; ay[1] += w1 * u.y; az[1] += w1 * u.z;
      ax[2] += w2 * u.x; ay[2] += w2 * u.y; az[2] += w2 * u.z;
      ax[3] += w3 * u.x; ay[3] += w3 * u.y; az[3] += w3 * u.z;
    }
  }
  {
    float* pp = part + (strip * 64 + k) * 16;
#pragma unroll
    for (int hd = 0; hd < 4; ++hd) {
      pp[hd] = agg[hd];
      pp[4 + hd * 3 + 0] = ax[hd];
      pp[4 + hd * 3 + 1] = ay[hd];
      pp[4 + hd * 3 + 2] = az[hd];
    }
  }
  __syncthreads();
  {
    // c = tid = kk*4 + hd (matches post_w1/vmix/node_w1 row order)
    int kk = tid >> 2, hd = tid & 3;
    float aggt = 0.f, cx = 0.f, cy = 0.f, cz = 0.f;
#pragma unroll
    for (int s2 = 0; s2 < 4; ++s2) {
      const float* pp = part + (s2 * 64 + kk) * 16;
      aggt += pp[hd];
      cx += pp[4 + hd * 3 + 0];
      cy += pp[4 + hd * 3 + 1];
      cz += pp[4 + hd * 3 + 2];
    }
    const float inv = 1.0f / 256.0f;
    cx *= inv; cy *= inv; cz *= inv;
    cn_l[tid]  = cx * cx + cy * cy + cz * cz;
    hag_l[tid] = aggt;
  }
  __syncthreads();

  // post MLP: comb_norm[256] -> 64 -> 64
  if (tid < 64) {
    float p = pb1[tid];
    for (int m = 0; m < 256; ++m) p += cn_l[m] * pw1[m * 64 + tid];
    m1[tid] = silu_f(p);
  }
  __syncthreads();
  if (tid < 64) {
    float p = pb2[tid];
    for (int m = 0; m < 64; ++m) p += m1[m] * pw2[m * 64 + tid];
    hcm[tid] = silu_f(p);
  }
  __syncthreads();
  // node MLP: concat(h, h_agg, h_comb) [384] -> 64 -> 64, residual
  if (tid < 64) {
    float p = nb1[tid];
    const float* hrow = h + (size_t)bi * 64;   // uniform scalar loads
    for (int f = 0; f < 64; ++f)  p += hrow[f] * nw1[f * 64 + tid];
    for (int m = 0; m < 256; ++m) p += hag_l[m] * nw1[(64 + m) * 64 + tid];
    for (int m = 0; m < 64; ++m)  p += hcm[m] * nw1[(320 + m) * 64 + tid];
    m1[tid] = silu_f(p);
  }
  __syncthreads();
  if (tid < 64) {
    float p = nb2[tid];
    for (int m = 0; m < 64; ++m) p += m1[m] * nw2[m * 64 + tid];
    float hn = h[(size_t)bi * 64 + tid] + silu_f(p);
    out[(size_t)bi * 64 + tid] = hn;
    hnw[tid] = hn;
  }
  __syncthreads();
  // velocity scale + coordinate/velocity outputs
  if (tid < 64) {
    float p = vb1[tid];
    for (int m = 0; m < 64; ++m) p += hnw[m] * vw1[m * 64 + tid];
    float vs = silu_f(p) * vw2[tid];
#pragma unroll
    for (int off = 32; off >= 1; off >>= 1) vs += __shfl_xor(vs, off);
    if (tid == 0) {
#pragma unroll
      for (int d = 0; d < 3; ++d) {
        float dvv = DV[bi * 3 + d];
        float vn = dvv + vs * v[bi * 3 + d];
        float xn = x[bi * 3 + d] + vn;
        out[32768 + bi * 3 + d] = xn;
        out[34304 + bi * 3 + d] = vn;
      }
    }
  }
}

extern "C" void kernel_launch(void* const* d_in, const int* in_sizes, int n_in,
                              void* d_out, int out_size, void* d_ws, size_t ws_size,
                              hipStream_t stream) {
  const float* h    = (const float*)d_in[0];
  const float* x    = (const float*)d_in[1];
  const float* v    = (const float*)d_in[2];
  const float* ew1  = (const float*)d_in[3];
  const float* eb1  = (const float*)d_in[4];
  const float* ew2  = (const float*)d_in[5];
  const float* eb2  = (const float*)d_in[6];
  const float* semw = (const float*)d_in[7];
  const float* semb = (const float*)d_in[8];
  const float* pw1  = (const float*)d_in[9];
  const float* pb1  = (const float*)d_in[10];
  const float* pw2  = (const float*)d_in[11];
  const float* pb2  = (const float*)d_in[12];
  const float* nw1  = (const float*)d_in[13];
  const float* nb1  = (const float*)d_in[14];
  const float* nw2  = (const float*)d_in[15];
  const float* nb2  = (const float*)d_in[16];
  const float* vw1  = (const float*)d_in[17];
  const float* vb1  = (const float*)d_in[18];
  const float* vw2  = (const float*)d_in[19];
  const float* vmix = (const float*)d_in[20];
  const float* lgam = (const float*)d_in[21];
  float* out = (float*)d_out;

  float* ws  = (float*)d_ws;
  float* A   = ws;                                   // 512*64
  float* Bm  = ws + 32768;                           // 512*64
  float* HE  = ws + 65536;                           // 2*256*256*64
  float* ATT = ws + 65536 + 8388608;                 // 2*256*256*4
  float* DV  = ws + 65536 + 8388608 + 524288;        // 2*256*3

  k_pre<<<512, 64, 0, stream>>>(h, ew1, A, Bm);
  k_edge<<<512, 256, 0, stream>>>(x, ew1, eb1, ew2, eb2, semw, semb, vmix, lgam,
                                  A, Bm, HE, ATT, DV);
  k_comb<<<512, 256, 0, stream>>>(h, x, v, pw1, pb1, pw2, pb2, nw1, nb1, nw2, nb2,
                                  vw1, vb1, vw2, HE, ATT, DV, out);
}

// Round 2
// 166.493 us; speedup vs baseline: 1.1428x; 1.1428x over previous
//
#include <hip/hip_runtime.h>
#include <math.h>

// B=2, N=256, F=64, H=64, HEADS=4, C=256
#define EPSV 1e-5f
#define INFV 1e5f

typedef short bf16x8 __attribute__((ext_vector_type(8)));
typedef float f32x4 __attribute__((ext_vector_type(4)));

__device__ __forceinline__ float silu_f(float v) { return v / (1.0f + __expf(-v)); }

__device__ __forceinline__ unsigned short f2bf(float f) {
  unsigned int u = __float_as_uint(f);
  u = (u + 0x7fffu + ((u >> 16) & 1u)) >> 16;   // RNE
  return (unsigned short)u;
}
__device__ __forceinline__ float bf2f(unsigned short h) {
  return __uint_as_float(((unsigned int)h) << 16);
}

// Block-wide reduction of float4 across 256 threads. op=0 sum, op=1 max.
__device__ __forceinline__ float4 br4(float4 v, int op, float4* sc) {
  const int tid = threadIdx.x;
#pragma unroll
  for (int off = 32; off >= 1; off >>= 1) {
    float ox = __shfl_xor(v.x, off);
    float oy = __shfl_xor(v.y, off);
    float oz = __shfl_xor(v.z, off);
    float ow = __shfl_xor(v.w, off);
    if (op) { v.x = fmaxf(v.x, ox); v.y = fmaxf(v.y, oy); v.z = fmaxf(v.z, oz); v.w = fmaxf(v.w, ow); }
    else    { v.x += ox; v.y += oy; v.z += oz; v.w += ow; }
  }
  if ((tid & 63) == 0) sc[tid >> 6] = v;
  __syncthreads();
  float4 r0 = sc[0], r1 = sc[1], r2 = sc[2], r3 = sc[3];
  if (op) {
    v.x = fmaxf(fmaxf(r0.x, r1.x), fmaxf(r2.x, r3.x));
    v.y = fmaxf(fmaxf(r0.y, r1.y), fmaxf(r2.y, r3.y));
    v.z = fmaxf(fmaxf(r0.z, r1.z), fmaxf(r2.z, r3.z));
    v.w = fmaxf(fmaxf(r0.w, r1.w), fmaxf(r2.w, r3.w));
  } else {
    v.x = r0.x + r1.x + r2.x + r3.x;
    v.y = r0.y + r1.y + r2.y + r3.y;
    v.z = r0.z + r1.z + r2.z + r3.z;
    v.w = r0.w + r1.w + r2.w + r3.w;
  }
  __syncthreads();
  return v;
}

// K1: per-node precompute A = h @ W1[:64], Bm = h @ W1[64:128]
__global__ void k_pre(const float* __restrict__ h, const float* __restrict__ ew1,
                      float* __restrict__ A, float* __restrict__ Bm) {
  __shared__ __align__(16) float hl[64];
  const int bn = blockIdx.x;
  const int kk = threadIdx.x;
  hl[kk] = h[(size_t)bn * 64 + kk];
  __syncthreads();
  float a = 0.f, bb = 0.f;
#pragma unroll 8
  for (int f = 0; f < 64; ++f) {
    float hv = hl[f];
    a  += hv * ew1[f * 64 + kk];
    bb += hv * ew1[(64 + f) * 64 + kk];
  }
  A[(size_t)bn * 64 + kk]  = a;
  Bm[(size_t)bn * 64 + kk] = bb;
}

// Fused: edge MLP (MFMA) + attentions + comb/agg reductions + tail MLPs + outputs.
// One block per (b,i), 256 threads (thread = j for per-pair phases).
__global__ __launch_bounds__(256) void k_fused(
    const float* __restrict__ h, const float* __restrict__ x, const float* __restrict__ v,
    const float* __restrict__ ew1, const float* __restrict__ eb1,
    const float* __restrict__ ew2, const float* __restrict__ eb2,
    const float* __restrict__ semw, const float* __restrict__ semb,
    const float* __restrict__ pw1, const float* __restrict__ pb1,
    const float* __restrict__ pw2, const float* __restrict__ pb2,
    const float* __restrict__ nw1, const float* __restrict__ nb1,
    const float* __restrict__ nw2, const float* __restrict__ nb2,
    const float* __restrict__ vw1, const float* __restrict__ vb1,
    const float* __restrict__ vw2, const float* __restrict__ vmix,
    const float* __restrict__ lgam,
    const float* __restrict__ A, const float* __restrict__ Bm,
    float* __restrict__ out) {

  // T (256 x 64, stride 72 bf16) then reused as HE (256 x 64, stride 68 bf16)
  __shared__ __align__(16) unsigned short TH[256 * 72];
  __shared__ __align__(16) unsigned short E2T[64 * 72];   // ew2^T bf16, stride 72
  __shared__ __align__(16) float4 unit_l[256];
  __shared__ __align__(16) float4 cat_l[256];
  __shared__ __align__(16) float part[4 * 64 * 16];
  __shared__ float4 sc[4];
  __shared__ float cn_l[256];
  __shared__ float hag_l[256];
  __shared__ float m1s[64];
  __shared__ float hcm[64];
  __shared__ float hnw[64];
  __shared__ float dvs[3];

  const int bi  = blockIdx.x;
  const int i   = bi & 255;
  const int tid = threadIdx.x;
  const int j   = tid;
  const int bj  = (bi & ~255) | j;

  // ---- Phase A: geometry + layer-1 (fp32) -> T (bf16), stage ew2^T ----
  const float xi0 = x[bi * 3 + 0], xi1 = x[bi * 3 + 1], xi2 = x[bi * 3 + 2];
  const float dx = x[bj * 3 + 0] - xi0;
  const float dy = x[bj * 3 + 1] - xi1;
  const float dz = x[bj * 3 + 2] - xi2;
  const float dn = sqrtf(dx * dx + dy * dy + dz * dz + EPSV);
  const float invn = 1.0f / (dn + EPSV);
  const float ux = dx * invn, uy = dy * invn, uz = dz * invn;
  unit_l[j] = make_float4(ux, uy, uz, 0.f);

#pragma unroll
  for (int q = 0; q < 16; ++q) {
    int idx = q * 256 + tid;
    int m = idx >> 6, n = idx & 63;
    E2T[n * 72 + m] = f2bf(ew2[m * 64 + n]);   // [n][m] = ew2[m][n]
  }

  {
    const float* __restrict__ Arow  = A + (size_t)bj * 64;
    const float* __restrict__ bmrow = Bm + (size_t)bi * 64;   // uniform
    const float* __restrict__ w1d   = ew1 + 128 * 64;
#pragma unroll
    for (int m0 = 0; m0 < 64; m0 += 4) {
      float4 av = *reinterpret_cast<const float4*>(Arow + m0);
      unsigned int t0 = f2bf(silu_f(av.x + bmrow[m0 + 0] + dn * w1d[m0 + 0] + eb1[m0 + 0]));
      unsigned int t1 = f2bf(silu_f(av.y + bmrow[m0 + 1] + dn * w1d[m0 + 1] + eb1[m0 + 1]));
      unsigned int t2 = f2bf(silu_f(av.z + bmrow[m0 + 2] + dn * w1d[m0 + 2] + eb1[m0 + 2]));
      unsigned int t3 = f2bf(silu_f(av.w + bmrow[m0 + 3] + dn * w1d[m0 + 3] + eb1[m0 + 3]));
      uint2 pk;
      pk.x = t0 | (t1 << 16);
      pk.y = t2 | (t3 << 16);
      *reinterpret_cast<uint2*>(&TH[j * 72 + m0]) = pk;
    }
  }
  __syncthreads();

  // ---- Phase B: HE[256x64] = T @ ew2 via MFMA 16x16x32 bf16 ----
  const int lid  = tid & 63;
  const int w    = tid >> 6;      // wave id -> row block 64w..64w+63
  const int l15  = lid & 15;
  const int quad = lid >> 4;

  f32x4 acc[4][4];
#pragma unroll
  for (int tr = 0; tr < 4; ++tr)
#pragma unroll
    for (int tc = 0; tc < 4; ++tc)
      acc[tr][tc] = (f32x4){0.f, 0.f, 0.f, 0.f};

#pragma unroll
  for (int ms = 0; ms < 64; ms += 32) {
    bf16x8 af[4], bfr[4];
#pragma unroll
    for (int tr = 0; tr < 4; ++tr)
      af[tr] = *reinterpret_cast<const bf16x8*>(&TH[(64 * w + 16 * tr + l15) * 72 + ms + quad * 8]);
#pragma unroll
    for (int tc = 0; tc < 4; ++tc)
      bfr[tc] = *reinterpret_cast<const bf16x8*>(&E2T[(16 * tc + l15) * 72 + ms + quad * 8]);
#pragma unroll
    for (int tr = 0; tr < 4; ++tr)
#pragma unroll
      for (int tc = 0; tc < 4; ++tc)
        acc[tr][tc] = __builtin_amdgcn_mfma_f32_16x16x32_bf16(af[tr], bfr[tc], acc[tr][tc], 0, 0, 0);
  }
  __syncthreads();   // T fully consumed; safe to overwrite with HE

  // ---- Phase B2: HE = silu(acc + eb2) -> TH (stride 68) ----
#pragma unroll
  for (int tc = 0; tc < 4; ++tc) {
    float bias = eb2[16 * tc + l15];
#pragma unroll
    for (int tr = 0; tr < 4; ++tr)
#pragma unroll
      for (int r = 0; r < 4; ++r) {
        int row = 64 * w + 16 * tr + quad * 4 + r;
        float val = silu_f(acc[tr][tc][r] + bias);
        TH[row * 68 + 16 * tc + l15] = f2bf(val);
      }
  }
  __syncthreads();

  // ---- Phase C: per-thread-j attention (3 softmaxes) + delta_v ----
  float he[64];
#pragma unroll
  for (int c = 0; c < 16; ++c) {
    uint2 u = *reinterpret_cast<const uint2*>(&TH[tid * 68 + c * 4]);
    he[c * 4 + 0] = __uint_as_float(u.x << 16);
    he[c * 4 + 1] = __uint_as_float(u.x & 0xffff0000u);
    he[c * 4 + 2] = __uint_as_float(u.y << 16);
    he[c * 4 + 3] = __uint_as_float(u.y & 0xffff0000u);
  }

  float4 sl = *reinterpret_cast<const float4*>(semb);
#pragma unroll
  for (int k = 0; k < 64; ++k) {
    float4 sw = *reinterpret_cast<const float4*>(semw + k * 4);
    sl.x += he[k] * sw.x; sl.y += he[k] * sw.y;
    sl.z += he[k] * sw.z; sl.w += he[k] * sw.w;
  }
  const float diag = (j == i) ? INFV : 0.0f;
  sl.x = ((sl.x > 0.f) ? sl.x : 0.2f * sl.x) - diag;
  sl.y = ((sl.y > 0.f) ? sl.y : 0.2f * sl.y) - diag;
  sl.z = ((sl.z > 0.f) ? sl.z : 0.2f * sl.z) - diag;
  sl.w = ((sl.w > 0.f) ? sl.w : 0.2f * sl.w) - diag;

  float4 lg = *reinterpret_cast<const float4*>(lgam);
  const float dni = dn + diag;
  float4 dl = make_float4(-dni * __expf(lg.x), -dni * __expf(lg.y),
                          -dni * __expf(lg.z), -dni * __expf(lg.w));

  float4 M = br4(dl, 1, sc);
  float4 e = make_float4(__expf(dl.x - M.x), __expf(dl.y - M.y),
                         __expf(dl.z - M.z), __expf(dl.w - M.w));
  float4 S = br4(e, 0, sc);
  float4 ea = make_float4(e.x / S.x, e.y / S.y, e.z / S.z, e.w / S.w);

  M = br4(sl, 1, sc);
  e = make_float4(__expf(sl.x - M.x), __expf(sl.y - M.y),
                  __expf(sl.z - M.z), __expf(sl.w - M.w));
  S = br4(e, 0, sc);
  float4 sa = make_float4(e.x / S.x, e.y / S.y, e.z / S.z, e.w / S.w);

  float4 p = make_float4(ea.x * sa.x, ea.y * sa.y, ea.z * sa.z, ea.w * sa.w);
  M = br4(p, 1, sc);
  e = make_float4(__expf(p.x - M.x), __expf(p.y - M.y),
                  __expf(p.z - M.z), __expf(p.w - M.w));
  S = br4(e, 0, sc);
  float4 catt = make_float4(e.x / S.x, e.y / S.y, e.z / S.z, e.w / S.w);

  cat_l[j] = catt;

  float s = 0.f;
#pragma unroll
  for (int k = 0; k < 64; ++k) {
    float4 vm = *reinterpret_cast<const float4*>(vmix + k * 4);
    s += he[k] * (catt.x * vm.x + catt.y * vm.y + catt.z * vm.z + catt.w * vm.w);
  }
  float4 dv = br4(make_float4(s * ux, s * uy, s * uz, 0.f), 0, sc);
  if (j == 0) {
    const float inv = 1.0f / 256.0f;
    dvs[0] = dv.x * inv; dvs[1] = dv.y * inv; dvs[2] = dv.z * inv;
  }
  __syncthreads();

  // ---- Phase D: comb_sum / h_agg strip reduction (thread = (strip, kcol)) ----
  const int kcol  = tid & 63;
  const int strip = tid >> 6;
  float agg[4] = {0.f, 0.f, 0.f, 0.f};
  float ax[4] = {0.f, 0.f, 0.f, 0.f};
  float ay[4] = {0.f, 0.f, 0.f, 0.f};
  float az[4] = {0.f, 0.f, 0.f, 0.f};
#pragma unroll 4
  for (int rr = 0; rr < 64; ++rr) {
    int jr = strip * 64 + rr;
    float hev = bf2f(TH[jr * 68 + kcol]);
    float4 ca = cat_l[jr];    // wave-uniform broadcast
    float4 u  = unit_l[jr];
    float w0 = hev * ca.x, w1 = hev * ca.y, w2 = hev * ca.z, w3 = hev * ca.w;
    agg[0] += w0; agg[1] += w1; agg[2] += w2; agg[3] += w3;
    ax[0] += w0 * u.x; ay[0] += w0 * u.y; az[0] += w0 * u.z;
    ax[1] += w1 * u.x; ay[1] += w1 * u.y; az[1] += w1 * u.z;
    ax[2] += w2 * u.x; ay[2] += w2 * u.y; az[2] += w2 * u.z;
    ax[3] += w3 * u.x; ay[3] += w3 * u.y; az[3] += w3 * u.z;
  }
  {
    float* pp = part + (strip * 64 + kcol) * 16;
#pragma unroll
    for (int hd = 0; hd < 4; ++hd) {
      pp[hd] = agg[hd];
      pp[4 + hd * 3 + 0] = ax[hd];
      pp[4 + hd * 3 + 1] = ay[hd];
      pp[4 + hd * 3 + 2] = az[hd];
    }
  }
  __syncthreads();
  {
    int kk = tid >> 2, hd = tid & 3;   // c = kk*4 + hd
    float aggt = 0.f, cx = 0.f, cy = 0.f, cz = 0.f;
#pragma unroll
    for (int s2 = 0; s2 < 4; ++s2) {
      const float* pp = part + (s2 * 64 + kk) * 16;
      aggt += pp[hd];
      cx += pp[4 + hd * 3 + 0];
      cy += pp[4 + hd * 3 + 1];
      cz += pp[4 + hd * 3 + 2];
    }
    const float inv = 1.0f / 256.0f;
    cx *= inv; cy *= inv; cz *= inv;
    cn_l[tid]  = cx * cx + cy * cy + cz * cz;
    hag_l[tid] = aggt;
  }
  __syncthreads();

  // ---- Phase E: post MLP ----
  if (tid < 64) {
    float pacc = pb1[tid];
    for (int m = 0; m < 256; ++m) pacc += cn_l[m] * pw1[m * 64 + tid];
    m1s[tid] = silu_f(pacc);
  }
  __syncthreads();
  if (tid < 64) {
    float pacc = pb2[tid];
    for (int m = 0; m < 64; ++m) pacc += m1s[m] * pw2[m * 64 + tid];
    hcm[tid] = silu_f(pacc);
  }
  __syncthreads();
  // ---- node MLP + residual ----
  if (tid < 64) {
    float pacc = nb1[tid];
    const float* hrow = h + (size_t)bi * 64;
    for (int f = 0; f < 64; ++f)  pacc += hrow[f] * nw1[f * 64 + tid];
    for (int m = 0; m < 256; ++m) pacc += hag_l[m] * nw1[(64 + m) * 64 + tid];
    for (int m = 0; m < 64; ++m)  pacc += hcm[m] * nw1[(320 + m) * 64 + tid];
    m1s[tid] = silu_f(pacc);
  }
  __syncthreads();
  if (tid < 64) {
    float pacc = nb2[tid];
    for (int m = 0; m < 64; ++m) pacc += m1s[m] * nw2[m * 64 + tid];
    float hn = h[(size_t)bi * 64 + tid] + silu_f(pacc);
    out[(size_t)bi * 64 + tid] = hn;
    hnw[tid] = hn;
  }
  __syncthreads();
  // ---- velocity scale + x/v outputs ----
  if (tid < 64) {
    float pacc = vb1[tid];
    for (int m = 0; m < 64; ++m) pacc += hnw[m] * vw1[m * 64 + tid];
    float vs = silu_f(pacc) * vw2[tid];
#pragma unroll
    for (int off = 32; off >= 1; off >>= 1) vs += __shfl_xor(vs, off);
    if (tid == 0) {
#pragma unroll
      for (int d = 0; d < 3; ++d) {
        float dvv = dvs[d];
        float vn = dvv + vs * v[bi * 3 + d];
        float xn = x[bi * 3 + d] + vn;
        out[32768 + bi * 3 + d] = xn;
        out[34304 + bi * 3 + d] = vn;
      }
    }
  }
}

extern "C" void kernel_launch(void* const* d_in, const int* in_sizes, int n_in,
                              void* d_out, int out_size, void* d_ws, size_t ws_size,
                              hipStream_t stream) {
  const float* h    = (const float*)d_in[0];
  const float* x    = (const float*)d_in[1];
  const float* v    = (const float*)d_in[2];
  const float* ew1  = (const float*)d_in[3];
  const float* eb1  = (const float*)d_in[4];
  const float* ew2  = (const float*)d_in[5];
  const float* eb2  = (const float*)d_in[6];
  const float* semw = (const float*)d_in[7];
  const float* semb = (const float*)d_in[8];
  const float* pw1  = (const float*)d_in[9];
  const float* pb1  = (const float*)d_in[10];
  const float* pw2  = (const float*)d_in[11];
  const float* pb2  = (const float*)d_in[12];
  const float* nw1  = (const float*)d_in[13];
  const float* nb1  = (const float*)d_in[14];
  const float* nw2  = (const float*)d_in[15];
  const float* nb2  = (const float*)d_in[16];
  const float* vw1  = (const float*)d_in[17];
  const float* vb1  = (const float*)d_in[18];
  const float* vw2  = (const float*)d_in[19];
  const float* vmix = (const float*)d_in[20];
  const float* lgam = (const float*)d_in[21];
  float* out = (float*)d_out;

  float* ws = (float*)d_ws;
  float* A  = ws;            // 512*64
  float* Bm = ws + 32768;    // 512*64

  k_pre<<<512, 64, 0, stream>>>(h, ew1, A, Bm);
  k_fused<<<512, 256, 0, stream>>>(h, x, v, ew1, eb1, ew2, eb2, semw, semb,
                                   pw1, pb1, pw2, pb2, nw1, nb1, nw2, nb2,
                                   vw1, vb1, vw2, vmix, lgam, A, Bm, out);
}

// Round 3
// 141.931 us; speedup vs baseline: 1.3406x; 1.1731x over previous
//
#include <hip/hip_runtime.h>
#include <math.h>

// B=2, N=256, F=64, H=64, HEADS=4, C=256
#define EPSV 1e-5f
#define INFV 1e5f

typedef short bf16x8 __attribute__((ext_vector_type(8)));
typedef float f32x4 __attribute__((ext_vector_type(4)));

__device__ __forceinline__ float silu_f(float v) { return v / (1.0f + __expf(-v)); }

__device__ __forceinline__ unsigned short f2bf(float f) {
  unsigned int u = __float_as_uint(f);
  u = (u + 0x7fffu + ((u >> 16) & 1u)) >> 16;   // RNE
  return (unsigned short)u;
}
__device__ __forceinline__ float bf2f(unsigned short h) {
  return __uint_as_float(((unsigned int)h) << 16);
}

// Block-wide reduction of float4 across 256 threads. op=0 sum, op=1 max.
__device__ __forceinline__ float4 br4(float4 v, int op, float4* sc) {
  const int tid = threadIdx.x;
#pragma unroll
  for (int off = 32; off >= 1; off >>= 1) {
    float ox = __shfl_xor(v.x, off);
    float oy = __shfl_xor(v.y, off);
    float oz = __shfl_xor(v.z, off);
    float ow = __shfl_xor(v.w, off);
    if (op) { v.x = fmaxf(v.x, ox); v.y = fmaxf(v.y, oy); v.z = fmaxf(v.z, oz); v.w = fmaxf(v.w, ow); }
    else    { v.x += ox; v.y += oy; v.z += oz; v.w += ow; }
  }
  if ((tid & 63) == 0) sc[tid >> 6] = v;
  __syncthreads();
  float4 r0 = sc[0], r1 = sc[1], r2 = sc[2], r3 = sc[3];
  if (op) {
    v.x = fmaxf(fmaxf(r0.x, r1.x), fmaxf(r2.x, r3.x));
    v.y = fmaxf(fmaxf(r0.y, r1.y), fmaxf(r2.y, r3.y));
    v.z = fmaxf(fmaxf(r0.z, r1.z), fmaxf(r2.z, r3.z));
    v.w = fmaxf(fmaxf(r0.w, r1.w), fmaxf(r2.w, r3.w));
  } else {
    v.x = r0.x + r1.x + r2.x + r3.x;
    v.y = r0.y + r1.y + r2.y + r3.y;
    v.z = r0.z + r1.z + r2.z + r3.z;
    v.w = r0.w + r1.w + r2.w + r3.w;
  }
  __syncthreads();
  return v;
}

// 64x64 @ 64x64 GEMM: A rows from TH (stride 72 u16), B cols from E2T (stride 72 u16).
__device__ __forceinline__ void gemm64(const unsigned short* TH, const unsigned short* E2T,
                                       int w, int l15, int quad, f32x4 acc[4][4]) {
#pragma unroll
  for (int tr = 0; tr < 4; ++tr)
#pragma unroll
    for (int tc = 0; tc < 4; ++tc)
      acc[tr][tc] = (f32x4){0.f, 0.f, 0.f, 0.f};
#pragma unroll
  for (int ms = 0; ms < 64; ms += 32) {
    bf16x8 af[4], bfr[4];
#pragma unroll
    for (int tr = 0; tr < 4; ++tr)
      af[tr] = *reinterpret_cast<const bf16x8*>(&TH[(64 * w + 16 * tr + l15) * 72 + ms + quad * 8]);
#pragma unroll
    for (int tc = 0; tc < 4; ++tc)
      bfr[tc] = *reinterpret_cast<const bf16x8*>(&E2T[(16 * tc + l15) * 72 + ms + quad * 8]);
#pragma unroll
    for (int tr = 0; tr < 4; ++tr)
#pragma unroll
      for (int tc = 0; tc < 4; ++tc)
        acc[tr][tc] = __builtin_amdgcn_mfma_f32_16x16x32_bf16(af[tr], bfr[tc], acc[tr][tc], 0, 0, 0);
  }
}

// Single fused kernel: one block per (b,i), 256 threads.
__global__ __launch_bounds__(256) void k_all(
    const float* __restrict__ h, const float* __restrict__ x, const float* __restrict__ v,
    const float* __restrict__ ew1, const float* __restrict__ eb1,
    const float* __restrict__ ew2, const float* __restrict__ eb2,
    const float* __restrict__ semw, const float* __restrict__ semb,
    const float* __restrict__ pw1, const float* __restrict__ pb1,
    const float* __restrict__ pw2, const float* __restrict__ pb2,
    const float* __restrict__ nw1, const float* __restrict__ nb1,
    const float* __restrict__ nw2, const float* __restrict__ nb2,
    const float* __restrict__ vw1, const float* __restrict__ vb1,
    const float* __restrict__ vw2, const float* __restrict__ vmix,
    const float* __restrict__ lgam, float* __restrict__ out) {

  // TH: h_b(bf16) -> T -> HE.  E2u: W1a^T / W2^T, then tail scratch.
  __shared__ __align__(16) unsigned short TH[256 * 72];
  __shared__ __align__(16) char E2u[9216];
  __shared__ __align__(16) float4 unit_l[256];
  __shared__ __align__(16) float4 cat_l[256];   // also P0 scratch for Bm partials
  __shared__ float dn_l[256];
  __shared__ float addk[64];    // Bm_i[k] + eb1[k]
  __shared__ float w1dk[64];    // ew1 distance row

  unsigned short* E2T = (unsigned short*)E2u;        // [64*72] during GEMMs
  float4* sc    = (float4*)E2u;                      // [8]   (post-GEMM2)
  float*  dvs   = (float*)(E2u + 128);               // [3]
  float*  cn_l  = (float*)(E2u + 256);               // [256]
  float*  hag_l = (float*)(E2u + 1280);              // [256]
  float*  tmp   = (float*)(E2u + 2304);              // [256]
  float*  m1s   = (float*)(E2u + 3328);              // [64]
  float*  hnw   = (float*)(E2u + 3584);              // [64]
  float*  nin   = (float*)(E2u + 4096);              // [384]

  const int bi  = blockIdx.x;
  const int i   = bi & 255;
  const int b0  = bi & ~255;
  const int tid = threadIdx.x;
  const int j   = tid;
  const int bj  = b0 | j;

  // ================= P0: staging =================
  // geometry (xi wave-uniform -> scalar)
  const float xi0 = x[bi * 3 + 0], xi1 = x[bi * 3 + 1], xi2 = x[bi * 3 + 2];
  const float dx = x[bj * 3 + 0] - xi0;
  const float dy = x[bj * 3 + 1] - xi1;
  const float dz = x[bj * 3 + 2] - xi2;
  const float dn = sqrtf(dx * dx + dy * dy + dz * dz + EPSV);
  const float invn = 1.0f / (dn + EPSV);
  const float ux = dx * invn, uy = dy * invn, uz = dz * invn;
  unit_l[j] = make_float4(ux, uy, uz, 0.f);
  dn_l[j] = dn;

  // stage h_b (coalesced float4) -> TH bf16, stride 72
  {
    const float4* hb4 = reinterpret_cast<const float4*>(h + (size_t)b0 * 64);
#pragma unroll
    for (int q = 0; q < 16; ++q) {
      int idx = q * 256 + tid;            // 0..4095 float4s
      float4 f4 = hb4[idx];
      int row = idx >> 4, c4 = idx & 15;
      uint2 pk;
      pk.x = (unsigned int)f2bf(f4.x) | ((unsigned int)f2bf(f4.y) << 16);
      pk.y = (unsigned int)f2bf(f4.z) | ((unsigned int)f2bf(f4.w) << 16);
      *reinterpret_cast<uint2*>(&TH[row * 72 + c4 * 4]) = pk;
    }
  }
  // stage W1a^T -> E2T
#pragma unroll
  for (int q = 0; q < 16; ++q) {
    int idx = q * 256 + tid;              // f*64+k, f<64
    E2T[(idx & 63) * 72 + (idx >> 6)] = f2bf(ew1[idx]);
  }
  // Bm_i partials (fp32 exact): thread (s,k), strip over f
  {
    int s = tid >> 6, k = tid & 63;
    const float* hrow = h + (size_t)bi * 64;      // uniform -> scalar loads
    float bp = 0.f;
#pragma unroll
    for (int f2 = 0; f2 < 16; ++f2) {
      int f = s * 16 + f2;
      bp += hrow[f] * ew1[(64 + f) * 64 + k];
    }
    reinterpret_cast<float*>(cat_l)[s * 64 + k] = bp;   // cat_l as scratch
  }
  __syncthreads();
  if (tid < 64) {
    const float* catf = reinterpret_cast<float*>(cat_l);
    addk[tid] = eb1[tid] + catf[tid] + catf[64 + tid] + catf[128 + tid] + catf[192 + tid];
    w1dk[tid] = ew1[128 * 64 + tid];
  }

  const int lid  = tid & 63;
  const int w    = tid >> 6;
  const int l15  = lid & 15;
  const int quad = lid >> 4;

  // ================= P1: GEMM1 (A-preact = h_b @ W1a) =================
  f32x4 acc[4][4];
  gemm64(TH, E2T, w, l15, quad, acc);
  __syncthreads();   // everyone done reading HB + W1a

  // epilogue: T = silu(A + Bm_i + dn*w1d + eb1) -> TH (stride 72)
#pragma unroll
  for (int tc = 0; tc < 4; ++tc) {
    float ak = addk[16 * tc + l15];
    float wd = w1dk[16 * tc + l15];
#pragma unroll
    for (int tr = 0; tr < 4; ++tr)
#pragma unroll
      for (int r = 0; r < 4; ++r) {
        int row = 64 * w + 16 * tr + quad * 4 + r;
        float val = silu_f(acc[tr][tc][r] + ak + dn_l[row] * wd);
        TH[row * 72 + 16 * tc + l15] = f2bf(val);
      }
  }
  // restage W2^T -> E2T
#pragma unroll
  for (int q = 0; q < 16; ++q) {
    int idx = q * 256 + tid;
    E2T[(idx & 63) * 72 + (idx >> 6)] = f2bf(ew2[idx]);
  }
  __syncthreads();

  // ================= P2: GEMM2 (HE = T @ W2) =================
  gemm64(TH, E2T, w, l15, quad, acc);
  __syncthreads();   // everyone done reading T + W2

  // epilogue: HE = silu(. + eb2) -> TH stride 68 (conflict-free write: 8*quad spread)
#pragma unroll
  for (int tc = 0; tc < 4; ++tc) {
    float b2 = eb2[16 * tc + l15];
#pragma unroll
    for (int tr = 0; tr < 4; ++tr)
#pragma unroll
      for (int r = 0; r < 4; ++r) {
        int row = 64 * w + 16 * tr + quad * 4 + r;
        TH[row * 68 + 16 * tc + l15] = f2bf(silu_f(acc[tr][tc][r] + b2));
      }
  }
  __syncthreads();

  // ================= P3: attentions (thread = j) =================
  float he[64];
#pragma unroll
  for (int c = 0; c < 16; ++c) {
    uint2 u = *reinterpret_cast<const uint2*>(&TH[tid * 68 + c * 4]);
    he[c * 4 + 0] = __uint_as_float(u.x << 16);
    he[c * 4 + 1] = __uint_as_float(u.x & 0xffff0000u);
    he[c * 4 + 2] = __uint_as_float(u.y << 16);
    he[c * 4 + 3] = __uint_as_float(u.y & 0xffff0000u);
  }

  float4 sl = *reinterpret_cast<const float4*>(semb);
#pragma unroll
  for (int k = 0; k < 64; ++k) {
    float4 sw = *reinterpret_cast<const float4*>(semw + k * 4);
    sl.x += he[k] * sw.x; sl.y += he[k] * sw.y;
    sl.z += he[k] * sw.z; sl.w += he[k] * sw.w;
  }
  const float diag = (j == i) ? INFV : 0.0f;
  sl.x = ((sl.x > 0.f) ? sl.x : 0.2f * sl.x) - diag;
  sl.y = ((sl.y > 0.f) ? sl.y : 0.2f * sl.y) - diag;
  sl.z = ((sl.z > 0.f) ? sl.z : 0.2f * sl.z) - diag;
  sl.w = ((sl.w > 0.f) ? sl.w : 0.2f * sl.w) - diag;

  float4 lg = *reinterpret_cast<const float4*>(lgam);
  const float dni = dn + diag;
  // euclid logits are <= 0: exp without max-subtraction is safe (diag underflows to 0)
  float4 e_eu = make_float4(__expf(-dni * __expf(lg.x)), __expf(-dni * __expf(lg.y)),
                            __expf(-dni * __expf(lg.z)), __expf(-dni * __expf(lg.w)));

  float4 M = br4(sl, 1, sc);
  float4 e_sem = make_float4(__expf(sl.x - M.x), __expf(sl.y - M.y),
                             __expf(sl.z - M.z), __expf(sl.w - M.w));

  // batched sums of e_eu and e_sem: one sync pair
  float4 a8 = e_eu, b8 = e_sem;
#pragma unroll
  for (int off = 32; off >= 1; off >>= 1) {
    a8.x += __shfl_xor(a8.x, off); a8.y += __shfl_xor(a8.y, off);
    a8.z += __shfl_xor(a8.z, off); a8.w += __shfl_xor(a8.w, off);
    b8.x += __shfl_xor(b8.x, off); b8.y += __shfl_xor(b8.y, off);
    b8.z += __shfl_xor(b8.z, off); b8.w += __shfl_xor(b8.w, off);
  }
  if ((tid & 63) == 0) { sc[tid >> 6] = a8; sc[4 + (tid >> 6)] = b8; }
  __syncthreads();
  float4 Se, Ss;
  {
    float4 r0 = sc[0], r1 = sc[1], r2 = sc[2], r3 = sc[3];
    Se = make_float4(r0.x + r1.x + r2.x + r3.x, r0.y + r1.y + r2.y + r3.y,
                     r0.z + r1.z + r2.z + r3.z, r0.w + r1.w + r2.w + r3.w);
    float4 s0 = sc[4], s1 = sc[5], s2 = sc[6], s3 = sc[7];
    Ss = make_float4(s0.x + s1.x + s2.x + s3.x, s0.y + s1.y + s2.y + s3.y,
                     s0.z + s1.z + s2.z + s3.z, s0.w + s1.w + s2.w + s3.w);
  }
  __syncthreads();

  // product softmax: p in [0,1] -> exp without max-subtraction is safe
  float4 p = make_float4((e_eu.x / Se.x) * (e_sem.x / Ss.x), (e_eu.y / Se.y) * (e_sem.y / Ss.y),
                         (e_eu.z / Se.z) * (e_sem.z / Ss.z), (e_eu.w / Se.w) * (e_sem.w / Ss.w));
  float4 ep = make_float4(__expf(p.x), __expf(p.y), __expf(p.z), __expf(p.w));
  float4 Sp = br4(ep, 0, sc);
  float4 catt = make_float4(ep.x / Sp.x, ep.y / Sp.y, ep.z / Sp.z, ep.w / Sp.w);
  cat_l[j] = catt;

  // delta_v
  float s = 0.f;
#pragma unroll
  for (int k = 0; k < 64; ++k) {
    float4 vm = *reinterpret_cast<const float4*>(vmix + k * 4);
    s += he[k] * (catt.x * vm.x + catt.y * vm.y + catt.z * vm.z + catt.w * vm.w);
  }
  float4 dv = br4(make_float4(s * ux, s * uy, s * uz, 0.f), 0, sc);
  if (j == 0) {
    const float inv = 1.0f / 256.0f;
    dvs[0] = dv.x * inv; dvs[1] = dv.y * inv; dvs[2] = dv.z * inv;
  }
  // br4 ended with a sync: cat_l visible to all

  // ========== P4: comb_sum / h_agg, wave-local (wave w -> k in [16w,16w+16)) ==========
  {
    const int kk = lid & 15;
    const int jq = lid >> 4;
    const int k  = 16 * w + kk;
    float agg[4] = {0.f, 0.f, 0.f, 0.f};
    float ax[4]  = {0.f, 0.f, 0.f, 0.f};
    float ay[4]  = {0.f, 0.f, 0.f, 0.f};
    float az[4]  = {0.f, 0.f, 0.f, 0.f};
#pragma unroll 4
    for (int jr2 = 0; jr2 < 64; ++jr2) {
      int jj = jq * 64 + ((jr2 + 4 * jq) & 63);   // swizzle: conflict-free TH reads
      float hev = bf2f(TH[jj * 68 + k]);
      float4 ca = cat_l[jj];
      float4 u  = unit_l[jj];
      float w0 = hev * ca.x, w1 = hev * ca.y, w2 = hev * ca.z, w3 = hev * ca.w;
      agg[0] += w0; agg[1] += w1; agg[2] += w2; agg[3] += w3;
      ax[0] += w0 * u.x; ay[0] += w0 * u.y; az[0] += w0 * u.z;
      ax[1] += w1 * u.x; ay[1] += w1 * u.y; az[1] += w1 * u.z;
      ax[2] += w2 * u.x; ay[2] += w2 * u.y; az[2] += w2 * u.z;
      ax[3] += w3 * u.x; ay[3] += w3 * u.y; az[3] += w3 * u.z;
    }
    // reduce over jq (lane bits 4,5)
#pragma unroll
    for (int off = 16; off <= 32; off <<= 1) {
#pragma unroll
      for (int hd = 0; hd < 4; ++hd) {
        agg[hd] += __shfl_xor(agg[hd], off);
        ax[hd]  += __shfl_xor(ax[hd], off);
        ay[hd]  += __shfl_xor(ay[hd], off);
        az[hd]  += __shfl_xor(az[hd], off);
      }
    }
    if (jq == 0) {
      const float inv = 1.0f / 256.0f;
#pragma unroll
      for (int hd = 0; hd < 4; ++hd) {
        float cx = ax[hd] * inv, cy = ay[hd] * inv, cz = az[hd] * inv;
        cn_l[k * 4 + hd]  = cx * cx + cy * cy + cz * cz;
        hag_l[k * 4 + hd] = agg[hd];
      }
    }
  }
  __syncthreads();

  // ================= P5: tail MLPs, strip-parallel (wave = strip) =================
  const int k = tid & 63;
  // post1: 256 -> 64
  {
    float a = 0.f;
    for (int m2 = 0; m2 < 64; ++m2) {
      int m = w * 64 + m2;
      a += cn_l[m] * pw1[m * 64 + k];
    }
    tmp[tid] = a;
  }
  __syncthreads();
  if (tid < 64) m1s[tid] = silu_f(pb1[tid] + tmp[tid] + tmp[64 + tid] + tmp[128 + tid] + tmp[192 + tid]);
  __syncthreads();
  // post2: 64 -> 64 (writes h_comb straight into nin[320..])
  {
    float a = 0.f;
#pragma unroll
    for (int m2 = 0; m2 < 16; ++m2) {
      int m = w * 16 + m2;
      a += m1s[m] * pw2[m * 64 + k];
    }
    tmp[tid] = a;
  }
  nin[64 + tid] = hag_l[tid];
  __syncthreads();
  if (tid < 64) {
    nin[tid] = h[(size_t)bi * 64 + tid];
    nin[320 + tid] = silu_f(pb2[tid] + tmp[tid] + tmp[64 + tid] + tmp[128 + tid] + tmp[192 + tid]);
  }
  __syncthreads();
  // node1: 384 -> 64
  {
    float a = 0.f;
    for (int m2 = 0; m2 < 96; ++m2) {
      int m = w * 96 + m2;
      a += nin[m] * nw1[m * 64 + k];
    }
    tmp[tid] = a;
  }
  __syncthreads();
  if (tid < 64) m1s[tid] = silu_f(nb1[tid] + tmp[tid] + tmp[64 + tid] + tmp[128 + tid] + tmp[192 + tid]);
  __syncthreads();
  // node2: 64 -> 64, residual, h_new out
  {
    float a = 0.f;
#pragma unroll
    for (int m2 = 0; m2 < 16; ++m2) {
      int m = w * 16 + m2;
      a += m1s[m] * nw2[m * 64 + k];
    }
    tmp[tid] = a;
  }
  __syncthreads();
  if (tid < 64) {
    float hn = h[(size_t)bi * 64 + tid] +
               silu_f(nb2[tid] + tmp[tid] + tmp[64 + tid] + tmp[128 + tid] + tmp[192 + tid]);
    out[(size_t)bi * 64 + tid] = hn;
    hnw[tid] = hn;
  }
  __syncthreads();
  // vel: 64 -> 64 -> scalar, then x/v outputs
  {
    float a = 0.f;
#pragma unroll
    for (int m2 = 0; m2 < 16; ++m2) {
      int m = w * 16 + m2;
      a += hnw[m] * vw1[m * 64 + k];
    }
    tmp[tid] = a;
  }
  __syncthreads();
  if (tid < 64) {
    float vh = silu_f(vb1[tid] + tmp[tid] + tmp[64 + tid] + tmp[128 + tid] + tmp[192 + tid]) * vw2[tid];
#pragma unroll
    for (int off = 32; off >= 1; off >>= 1) vh += __shfl_xor(vh, off);
    if (tid == 0) {
#pragma unroll
      for (int d = 0; d < 3; ++d) {
        float vn = dvs[d] + vh * v[bi * 3 + d];
        out[32768 + bi * 3 + d] = x[bi * 3 + d] + vn;
        out[34304 + bi * 3 + d] = vn;
      }
    }
  }
}

extern "C" void kernel_launch(void* const* d_in, const int* in_sizes, int n_in,
                              void* d_out, int out_size, void* d_ws, size_t ws_size,
                              hipStream_t stream) {
  const float* h    = (const float*)d_in[0];
  const float* x    = (const float*)d_in[1];
  const float* v    = (const float*)d_in[2];
  const float* ew1  = (const float*)d_in[3];
  const float* eb1  = (const float*)d_in[4];
  const float* ew2  = (const float*)d_in[5];
  const float* eb2  = (const float*)d_in[6];
  const float* semw = (const float*)d_in[7];
  const float* semb = (const float*)d_in[8];
  const float* pw1  = (const float*)d_in[9];
  const float* pb1  = (const float*)d_in[10];
  const float* pw2  = (const float*)d_in[11];
  const float* pb2  = (const float*)d_in[12];
  const float* nw1  = (const float*)d_in[13];
  const float* nb1  = (const float*)d_in[14];
  const float* nw2  = (const float*)d_in[15];
  const float* nb2  = (const float*)d_in[16];
  const float* vw1  = (const float*)d_in[17];
  const float* vb1  = (const float*)d_in[18];
  const float* vw2  = (const float*)d_in[19];
  const float* vmix = (const float*)d_in[20];
  const float* lgam = (const float*)d_in[21];
  float* out = (float*)d_out;

  k_all<<<512, 256, 0, stream>>>(h, x, v, ew1, eb1, ew2, eb2, semw, semb,
                                 pw1, pb1, pw2, pb2, nw1, nb1, nw2, nb2,
                                 vw1, vb1, vw2, vmix, lgam, out);
}

// Round 4
// 141.649 us; speedup vs baseline: 1.3433x; 1.0020x over previous
//
#include <hip/hip_runtime.h>
#include <hip/hip_bf16.h>
#include <math.h>

// B=2, N=256, F=64, H=64, HEADS=4, C=256
#define EPSV 1e-5f
#define INFV 1e5f

typedef short bf16x8 __attribute__((ext_vector_type(8)));
typedef float f32x4 __attribute__((ext_vector_type(4)));

__device__ __forceinline__ float rcp_f(float x) { return __builtin_amdgcn_rcpf(x); }
__device__ __forceinline__ float silu_f(float v) { return v * rcp_f(1.0f + __expf(-v)); }

__device__ __forceinline__ unsigned short f2bf(float f) {
  unsigned int u = __float_as_uint(f);
  u = (u + 0x7fffu + ((u >> 16) & 1u)) >> 16;   // RNE
  return (unsigned short)u;
}
__device__ __forceinline__ float bf2f(unsigned short h) {
  return __uint_as_float(((unsigned int)h) << 16);
}
__device__ __forceinline__ unsigned int pkbf(float a, float b) {
  float2 f2; f2.x = a; f2.y = b;
  __hip_bfloat162 t = __float22bfloat162_rn(f2);
  unsigned int u;
  __builtin_memcpy(&u, &t, 4);
  return u;
}

// Block-wide reduction of float4 across 256 threads. op=0 sum, op=1 max.
__device__ __forceinline__ float4 br4(float4 v, int op, float4* sc) {
  const int tid = threadIdx.x;
#pragma unroll
  for (int off = 32; off >= 1; off >>= 1) {
    float ox = __shfl_xor(v.x, off);
    float oy = __shfl_xor(v.y, off);
    float oz = __shfl_xor(v.z, off);
    float ow = __shfl_xor(v.w, off);
    if (op) { v.x = fmaxf(v.x, ox); v.y = fmaxf(v.y, oy); v.z = fmaxf(v.z, oz); v.w = fmaxf(v.w, ow); }
    else    { v.x += ox; v.y += oy; v.z += oz; v.w += ow; }
  }
  if ((tid & 63) == 0) sc[tid >> 6] = v;
  __syncthreads();
  float4 r0 = sc[0], r1 = sc[1], r2 = sc[2], r3 = sc[3];
  if (op) {
    v.x = fmaxf(fmaxf(r0.x, r1.x), fmaxf(r2.x, r3.x));
    v.y = fmaxf(fmaxf(r0.y, r1.y), fmaxf(r2.y, r3.y));
    v.z = fmaxf(fmaxf(r0.z, r1.z), fmaxf(r2.z, r3.z));
    v.w = fmaxf(fmaxf(r0.w, r1.w), fmaxf(r2.w, r3.w));
  } else {
    v.x = r0.x + r1.x + r2.x + r3.x;
    v.y = r0.y + r1.y + r2.y + r3.y;
    v.z = r0.z + r1.z + r2.z + r3.z;
    v.w = r0.w + r1.w + r2.w + r3.w;
  }
  __syncthreads();
  return v;
}

// 64x64 @ 64x64 GEMM: A rows from TH (stride 72 u16), B cols from E2T (stride 72 u16).
__device__ __forceinline__ void gemm64(const unsigned short* TH, const unsigned short* E2T,
                                       int w, int l15, int quad, f32x4 acc[4][4]) {
#pragma unroll
  for (int tr = 0; tr < 4; ++tr)
#pragma unroll
    for (int tc = 0; tc < 4; ++tc)
      acc[tr][tc] = (f32x4){0.f, 0.f, 0.f, 0.f};
#pragma unroll
  for (int ms = 0; ms < 64; ms += 32) {
    bf16x8 af[4], bfr[4];
#pragma unroll
    for (int tr = 0; tr < 4; ++tr)
      af[tr] = *reinterpret_cast<const bf16x8*>(&TH[(64 * w + 16 * tr + l15) * 72 + ms + quad * 8]);
#pragma unroll
    for (int tc = 0; tc < 4; ++tc)
      bfr[tc] = *reinterpret_cast<const bf16x8*>(&E2T[(16 * tc + l15) * 72 + ms + quad * 8]);
#pragma unroll
    for (int tr = 0; tr < 4; ++tr)
#pragma unroll
      for (int tc = 0; tc < 4; ++tc)
        acc[tr][tc] = __builtin_amdgcn_mfma_f32_16x16x32_bf16(af[tr], bfr[tc], acc[tr][tc], 0, 0, 0);
  }
}

// Kernel A: per (b,i) block, 256 threads. Edge MLP (2 MFMA GEMMs) + sem/vmix GEMM
// + attentions + comb/agg reductions. Writes cn[256], hag[256], dv[3] per i to ws.
__global__ __launch_bounds__(256) void k_pair(
    const float* __restrict__ h, const float* __restrict__ x,
    const float* __restrict__ ew1, const float* __restrict__ eb1,
    const float* __restrict__ ew2, const float* __restrict__ eb2,
    const float* __restrict__ semw, const float* __restrict__ semb,
    const float* __restrict__ vmix, const float* __restrict__ lgam,
    float* __restrict__ CN, float* __restrict__ HAG, float* __restrict__ DVW) {

  __shared__ __align__(16) unsigned short TH[256 * 72];   // h_b -> T -> HE (bf16)
  __shared__ __align__(16) unsigned short E2T[64 * 72];   // W1a^T / W2^T / E3T
  __shared__ __align__(16) float sd[256 * 8];             // sem+vmix GEMM out
  __shared__ __align__(16) float4 unit_l[256];
  __shared__ __align__(16) float4 cat_l[256];             // also Bm scratch
  __shared__ float dn_l[256];
  __shared__ float addk[64];
  __shared__ float w1dk[64];
  __shared__ float4 sc[8];

  const int bi  = blockIdx.x;
  const int i   = bi & 255;
  const int b0  = bi & ~255;
  const int tid = threadIdx.x;
  const int j   = tid;
  const int bj  = b0 | j;

  // ================= P0: staging =================
  const float xi0 = x[bi * 3 + 0], xi1 = x[bi * 3 + 1], xi2 = x[bi * 3 + 2];
  const float dx = x[bj * 3 + 0] - xi0;
  const float dy = x[bj * 3 + 1] - xi1;
  const float dz = x[bj * 3 + 2] - xi2;
  const float dn = sqrtf(dx * dx + dy * dy + dz * dz + EPSV);
  const float invn = rcp_f(dn + EPSV);
  const float ux = dx * invn, uy = dy * invn, uz = dz * invn;
  unit_l[j] = make_float4(ux, uy, uz, 0.f);
  dn_l[j] = dn;

  {
    const float4* hb4 = reinterpret_cast<const float4*>(h + (size_t)b0 * 64);
#pragma unroll
    for (int q = 0; q < 16; ++q) {
      int idx = q * 256 + tid;            // 0..4095 float4s
      float4 f4 = hb4[idx];
      int row = idx >> 4, c4 = idx & 15;
      uint2 pk;
      pk.x = pkbf(f4.x, f4.y);
      pk.y = pkbf(f4.z, f4.w);
      *reinterpret_cast<uint2*>(&TH[row * 72 + c4 * 4]) = pk;
    }
  }
  // stage W1a^T
#pragma unroll
  for (int q = 0; q < 16; ++q) {
    int idx = q * 256 + tid;              // f*64+k
    E2T[(idx & 63) * 72 + (idx >> 6)] = f2bf(ew1[idx]);
  }
  // Bm_i partials (fp32 exact)
  {
    int s = tid >> 6, k = tid & 63;
    const float* hrow = h + (size_t)bi * 64;      // uniform -> scalar loads
    float bp = 0.f;
#pragma unroll
    for (int f2 = 0; f2 < 16; ++f2) {
      int f = s * 16 + f2;
      bp += hrow[f] * ew1[(64 + f) * 64 + k];
    }
    reinterpret_cast<float*>(cat_l)[s * 64 + k] = bp;
  }
  __syncthreads();
  if (tid < 64) {
    const float* catf = reinterpret_cast<float*>(cat_l);
    addk[tid] = eb1[tid] + catf[tid] + catf[64 + tid] + catf[128 + tid] + catf[192 + tid];
    w1dk[tid] = ew1[128 * 64 + tid];
  }

  const int lid  = tid & 63;
  const int w    = tid >> 6;
  const int l15  = lid & 15;
  const int quad = lid >> 4;

  // ================= P1: GEMM1 (h_b @ W1a) =================
  f32x4 acc[4][4];
  gemm64(TH, E2T, w, l15, quad, acc);
  __syncthreads();

  // epilogue: T = silu(A + Bm_i + dn*w1d + eb1)
#pragma unroll
  for (int tc = 0; tc < 4; ++tc) {
    float ak = addk[16 * tc + l15];
    float wd = w1dk[16 * tc + l15];
#pragma unroll
    for (int tr = 0; tr < 4; ++tr)
#pragma unroll
      for (int r = 0; r < 4; ++r) {
        int row = 64 * w + 16 * tr + quad * 4 + r;
        float val = silu_f(acc[tr][tc][r] + ak + dn_l[row] * wd);
        TH[row * 72 + 16 * tc + l15] = f2bf(val);
      }
  }
  // restage W2^T
#pragma unroll
  for (int q = 0; q < 16; ++q) {
    int idx = q * 256 + tid;
    E2T[(idx & 63) * 72 + (idx >> 6)] = f2bf(ew2[idx]);
  }
  __syncthreads();

  // ================= P2: GEMM2 (HE = T @ W2) =================
  gemm64(TH, E2T, w, l15, quad, acc);
  __syncthreads();

  // epilogue: HE = silu(. + eb2) -> TH stride 72;  stage E3T = [semw | vmix]^T
#pragma unroll
  for (int tc = 0; tc < 4; ++tc) {
    float b2 = eb2[16 * tc + l15];
#pragma unroll
    for (int tr = 0; tr < 4; ++tr)
#pragma unroll
      for (int r = 0; r < 4; ++r) {
        int row = 64 * w + 16 * tr + quad * 4 + r;
        TH[row * 72 + 16 * tc + l15] = f2bf(silu_f(acc[tr][tc][r] + b2));
      }
  }
#pragma unroll
  for (int q = 0; q < 2; ++q) {
    int idx = q * 256 + tid;          // 0..511: n = idx>>6 (0..7), kk = idx&63
    int n = idx >> 6, kk = idx & 63;
    float wv = (n < 4) ? semw[kk * 4 + n] : vmix[kk * 4 + (n - 4)];
    E2T[n * 72 + kk] = f2bf(wv);
  }
  __syncthreads();

  // ================= P2b: GEMM3 (HE @ [semw|vmix]) -> sd[256][8] =================
  {
    f32x4 acc3[4];
#pragma unroll
    for (int tr = 0; tr < 4; ++tr) acc3[tr] = (f32x4){0.f, 0.f, 0.f, 0.f};
#pragma unroll
    for (int ms = 0; ms < 64; ms += 32) {
      bf16x8 b3 = *reinterpret_cast<const bf16x8*>(&E2T[l15 * 72 + ms + quad * 8]);
#pragma unroll
      for (int tr = 0; tr < 4; ++tr) {
        bf16x8 a3 = *reinterpret_cast<const bf16x8*>(&TH[(64 * w + 16 * tr + l15) * 72 + ms + quad * 8]);
        acc3[tr] = __builtin_amdgcn_mfma_f32_16x16x32_bf16(a3, b3, acc3[tr], 0, 0, 0);
      }
    }
    if (l15 < 8) {
#pragma unroll
      for (int tr = 0; tr < 4; ++tr)
#pragma unroll
        for (int r = 0; r < 4; ++r)
          sd[(64 * w + 16 * tr + quad * 4 + r) * 8 + l15] = acc3[tr][r];
    }
  }
  __syncthreads();

  // ================= P3: attentions (thread = j) =================
  float4 s01 = *reinterpret_cast<const float4*>(sd + j * 8);       // sem logits (pre-bias)
  float4 s23 = *reinterpret_cast<const float4*>(sd + j * 8 + 4);   // vmix dots d[hd]
  float4 sbv = *reinterpret_cast<const float4*>(semb);
  const float diag = (j == i) ? INFV : 0.0f;
  float4 sl;
  sl.x = s01.x + sbv.x; sl.y = s01.y + sbv.y; sl.z = s01.z + sbv.z; sl.w = s01.w + sbv.w;
  sl.x = ((sl.x > 0.f) ? sl.x : 0.2f * sl.x) - diag;
  sl.y = ((sl.y > 0.f) ? sl.y : 0.2f * sl.y) - diag;
  sl.z = ((sl.z > 0.f) ? sl.z : 0.2f * sl.z) - diag;
  sl.w = ((sl.w > 0.f) ? sl.w : 0.2f * sl.w) - diag;

  float4 lg = *reinterpret_cast<const float4*>(lgam);
  const float dni = dn + diag;
  // euclid logits <= 0: exp without max-subtraction safe (diag underflows to 0)
  float4 e_eu = make_float4(__expf(-dni * __expf(lg.x)), __expf(-dni * __expf(lg.y)),
                            __expf(-dni * __expf(lg.z)), __expf(-dni * __expf(lg.w)));

  float4 M = br4(sl, 1, sc);
  float4 e_sem = make_float4(__expf(sl.x - M.x), __expf(sl.y - M.y),
                             __expf(sl.z - M.z), __expf(sl.w - M.w));

  // batched sums of e_eu and e_sem
  float4 a8 = e_eu, b8 = e_sem;
#pragma unroll
  for (int off = 32; off >= 1; off >>= 1) {
    a8.x += __shfl_xor(a8.x, off); a8.y += __shfl_xor(a8.y, off);
    a8.z += __shfl_xor(a8.z, off); a8.w += __shfl_xor(a8.w, off);
    b8.x += __shfl_xor(b8.x, off); b8.y += __shfl_xor(b8.y, off);
    b8.z += __shfl_xor(b8.z, off); b8.w += __shfl_xor(b8.w, off);
  }
  if ((tid & 63) == 0) { sc[tid >> 6] = a8; sc[4 + (tid >> 6)] = b8; }
  __syncthreads();
  float4 Se, Ss;
  {
    float4 r0 = sc[0], r1 = sc[1], r2 = sc[2], r3 = sc[3];
    Se = make_float4(r0.x + r1.x + r2.x + r3.x, r0.y + r1.y + r2.y + r3.y,
                     r0.z + r1.z + r2.z + r3.z, r0.w + r1.w + r2.w + r3.w);
    float4 s0 = sc[4], s1 = sc[5], s2 = sc[6], s3 = sc[7];
    Ss = make_float4(s0.x + s1.x + s2.x + s3.x, s0.y + s1.y + s2.y + s3.y,
                     s0.z + s1.z + s2.z + s3.z, s0.w + s1.w + s2.w + s3.w);
  }
  __syncthreads();

  float4 p = make_float4((e_eu.x * rcp_f(Se.x)) * (e_sem.x * rcp_f(Ss.x)),
                         (e_eu.y * rcp_f(Se.y)) * (e_sem.y * rcp_f(Ss.y)),
                         (e_eu.z * rcp_f(Se.z)) * (e_sem.z * rcp_f(Ss.z)),
                         (e_eu.w * rcp_f(Se.w)) * (e_sem.w * rcp_f(Ss.w)));
  float4 ep = make_float4(__expf(p.x), __expf(p.y), __expf(p.z), __expf(p.w));
  float4 Sp = br4(ep, 0, sc);
  float4 catt = make_float4(ep.x * rcp_f(Sp.x), ep.y * rcp_f(Sp.y),
                            ep.z * rcp_f(Sp.z), ep.w * rcp_f(Sp.w));
  cat_l[j] = catt;

  // delta_v: s_j = sum_hd catt[hd] * d[hd]
  float s = catt.x * s23.x + catt.y * s23.y + catt.z * s23.z + catt.w * s23.w;
  float4 dv = br4(make_float4(s * ux, s * uy, s * uz, 0.f), 0, sc);
  if (j == 0) {
    const float inv = 1.0f / 256.0f;
    DVW[bi * 3 + 0] = dv.x * inv;
    DVW[bi * 3 + 1] = dv.y * inv;
    DVW[bi * 3 + 2] = dv.z * inv;
  }
  // br4 ended with a sync: cat_l visible

  // ========== P4: comb_sum / h_agg, wave-local (wave w -> k in [16w,16w+16)) ==========
  {
    const int kk = lid & 15;
    const int jq = lid >> 4;
    const int k  = 16 * w + kk;
    float agg[4] = {0.f, 0.f, 0.f, 0.f};
    float ax[4]  = {0.f, 0.f, 0.f, 0.f};
    float ay[4]  = {0.f, 0.f, 0.f, 0.f};
    float az[4]  = {0.f, 0.f, 0.f, 0.f};
#pragma unroll 4
    for (int jr2 = 0; jr2 < 64; ++jr2) {
      int jj = jq * 64 + ((jr2 + 4 * jq) & 63);
      float hev = bf2f(TH[jj * 72 + k]);
      float4 ca = cat_l[jj];
      float4 u  = unit_l[jj];
      float w0 = hev * ca.x, w1 = hev * ca.y, w2 = hev * ca.z, w3 = hev * ca.w;
      agg[0] += w0; agg[1] += w1; agg[2] += w2; agg[3] += w3;
      ax[0] += w0 * u.x; ay[0] += w0 * u.y; az[0] += w0 * u.z;
      ax[1] += w1 * u.x; ay[1] += w1 * u.y; az[1] += w1 * u.z;
      ax[2] += w2 * u.x; ay[2] += w2 * u.y; az[2] += w2 * u.z;
      ax[3] += w3 * u.x; ay[3] += w3 * u.y; az[3] += w3 * u.z;
    }
#pragma unroll
    for (int off = 16; off <= 32; off <<= 1) {
#pragma unroll
      for (int hd = 0; hd < 4; ++hd) {
        agg[hd] += __shfl_xor(agg[hd], off);
        ax[hd]  += __shfl_xor(ax[hd], off);
        ay[hd]  += __shfl_xor(ay[hd], off);
        az[hd]  += __shfl_xor(az[hd], off);
      }
    }
    if (jq == 0) {
      const float inv = 1.0f / 256.0f;
      f32x4 cnv, hgv;
#pragma unroll
      for (int hd = 0; hd < 4; ++hd) {
        float cx = ax[hd] * inv, cy = ay[hd] * inv, cz = az[hd] * inv;
        cnv[hd] = cx * cx + cy * cy + cz * cz;
        hgv[hd] = agg[hd];
      }
      *reinterpret_cast<f32x4*>(CN  + (size_t)bi * 256 + k * 4) = cnv;
      *reinterpret_cast<f32x4*>(HAG + (size_t)bi * 256 + k * 4) = hgv;
    }
  }
}

// Kernel B: batched tail MLPs. One block per (b,i), 64 threads (one wave).
__global__ __launch_bounds__(64) void k_tail(
    const float* __restrict__ h, const float* __restrict__ x, const float* __restrict__ v,
    const float* __restrict__ pw1, const float* __restrict__ pb1,
    const float* __restrict__ pw2, const float* __restrict__ pb2,
    const float* __restrict__ nw1, const float* __restrict__ nb1,
    const float* __restrict__ nw2, const float* __restrict__ nb2,
    const float* __restrict__ vw1, const float* __restrict__ vb1,
    const float* __restrict__ vw2,
    const float* __restrict__ CN, const float* __restrict__ HAG,
    const float* __restrict__ DVW, float* __restrict__ out) {
  __shared__ __align__(16) float cn_s[256];
  __shared__ __align__(16) float hag_s[256];
  __shared__ float h_s[64];
  __shared__ float m1[64];
  __shared__ float hc[64];
  __shared__ float hn_s[64];

  const int bi = blockIdx.x;
  const int k  = threadIdx.x;

  reinterpret_cast<float4*>(cn_s)[k]  = reinterpret_cast<const float4*>(CN  + (size_t)bi * 256)[k];
  reinterpret_cast<float4*>(hag_s)[k] = reinterpret_cast<const float4*>(HAG + (size_t)bi * 256)[k];
  h_s[k] = h[(size_t)bi * 64 + k];
  __syncthreads();

  // post1: 256 -> 64
  float a = pb1[k];
  for (int m = 0; m < 256; ++m) a += cn_s[m] * pw1[m * 64 + k];
  m1[k] = silu_f(a);
  __syncthreads();
  // post2: 64 -> 64
  a = pb2[k];
#pragma unroll 8
  for (int m = 0; m < 64; ++m) a += m1[m] * pw2[m * 64 + k];
  hc[k] = silu_f(a);
  __syncthreads();
  // node1: 384 -> 64
  a = nb1[k];
#pragma unroll 4
  for (int m = 0; m < 64; ++m)  a += h_s[m] * nw1[m * 64 + k];
  for (int m = 0; m < 256; ++m) a += hag_s[m] * nw1[(64 + m) * 64 + k];
#pragma unroll 4
  for (int m = 0; m < 64; ++m)  a += hc[m] * nw1[(320 + m) * 64 + k];
  m1[k] = silu_f(a);
  __syncthreads();
  // node2: 64 -> 64, residual
  a = nb2[k];
#pragma unroll 8
  for (int m = 0; m < 64; ++m) a += m1[m] * nw2[m * 64 + k];
  float hn = h_s[k] + silu_f(a);
  out[(size_t)bi * 64 + k] = hn;
  hn_s[k] = hn;
  __syncthreads();
  // vel: 64 -> 64 -> scalar
  a = vb1[k];
#pragma unroll 8
  for (int m = 0; m < 64; ++m) a += hn_s[m] * vw1[m * 64 + k];
  float vh = silu_f(a) * vw2[k];
#pragma unroll
  for (int off = 32; off >= 1; off >>= 1) vh += __shfl_xor(vh, off);
  if (k == 0) {
#pragma unroll
    for (int d = 0; d < 3; ++d) {
      float vn = DVW[bi * 3 + d] + vh * v[bi * 3 + d];
      out[32768 + bi * 3 + d] = x[bi * 3 + d] + vn;
      out[34304 + bi * 3 + d] = vn;
    }
  }
}

extern "C" void kernel_launch(void* const* d_in, const int* in_sizes, int n_in,
                              void* d_out, int out_size, void* d_ws, size_t ws_size,
                              hipStream_t stream) {
  const float* h    = (const float*)d_in[0];
  const float* x    = (const float*)d_in[1];
  const float* v    = (const float*)d_in[2];
  const float* ew1  = (const float*)d_in[3];
  const float* eb1  = (const float*)d_in[4];
  const float* ew2  = (const float*)d_in[5];
  const float* eb2  = (const float*)d_in[6];
  const float* semw = (const float*)d_in[7];
  const float* semb = (const float*)d_in[8];
  const float* pw1  = (const float*)d_in[9];
  const float* pb1  = (const float*)d_in[10];
  const float* pw2  = (const float*)d_in[11];
  const float* pb2  = (const float*)d_in[12];
  const float* nw1  = (const float*)d_in[13];
  const float* nb1  = (const float*)d_in[14];
  const float* nw2  = (const float*)d_in[15];
  const float* nb2  = (const float*)d_in[16];
  const float* vw1  = (const float*)d_in[17];
  const float* vb1  = (const float*)d_in[18];
  const float* vw2  = (const float*)d_in[19];
  const float* vmix = (const float*)d_in[20];
  const float* lgam = (const float*)d_in[21];
  float* out = (float*)d_out;

  float* ws  = (float*)d_ws;
  float* CN  = ws;                 // 512*256
  float* HAG = ws + 131072;        // 512*256
  float* DVW = ws + 262144;        // 512*3

  k_pair<<<512, 256, 0, stream>>>(h, x, ew1, eb1, ew2, eb2, semw, semb,
                                  vmix, lgam, CN, HAG, DVW);
  k_tail<<<512, 64, 0, stream>>>(h, x, v, pw1, pb1, pw2, pb2, nw1, nb1, nw2, nb2,
                                 vw1, vb1, vw2, CN, HAG, DVW, out);
}

// Round 5
// 121.917 us; speedup vs baseline: 1.5607x; 1.1618x over previous
//
#include <hip/hip_runtime.h>
#include <hip/hip_bf16.h>
#include <math.h>

// B=2, N=256, F=64, H=64, HEADS=4, C=256
#define EPSV 1e-5f
#define INFV 1e5f

typedef short bf16x8 __attribute__((ext_vector_type(8)));
typedef float f32x4 __attribute__((ext_vector_type(4)));

__device__ __forceinline__ float rcp_f(float x) { return __builtin_amdgcn_rcpf(x); }
__device__ __forceinline__ float silu_f(float v) { return v * rcp_f(1.0f + __expf(-v)); }

__device__ __forceinline__ unsigned short f2bf(float f) {
  unsigned int u = __float_as_uint(f);
  u = (u + 0x7fffu + ((u >> 16) & 1u)) >> 16;   // RNE
  return (unsigned short)u;
}
__device__ __forceinline__ float bf2f(unsigned short h) {
  return __uint_as_float(((unsigned int)h) << 16);
}
__device__ __forceinline__ unsigned int pkbf(float a, float b) {
  float2 f2; f2.x = a; f2.y = b;
  __hip_bfloat162 t = __float22bfloat162_rn(f2);
  unsigned int u;
  __builtin_memcpy(&u, &t, 4);
  return u;
}

// Block-wide reduction of float4 across 256 threads. op=0 sum, op=1 max.
__device__ __forceinline__ float4 br4(float4 v, int op, float4* sc) {
  const int tid = threadIdx.x;
#pragma unroll
  for (int off = 32; off >= 1; off >>= 1) {
    float ox = __shfl_xor(v.x, off);
    float oy = __shfl_xor(v.y, off);
    float oz = __shfl_xor(v.z, off);
    float ow = __shfl_xor(v.w, off);
    if (op) { v.x = fmaxf(v.x, ox); v.y = fmaxf(v.y, oy); v.z = fmaxf(v.z, oz); v.w = fmaxf(v.w, ow); }
    else    { v.x += ox; v.y += oy; v.z += oz; v.w += ow; }
  }
  if ((tid & 63) == 0) sc[tid >> 6] = v;
  __syncthreads();
  float4 r0 = sc[0], r1 = sc[1], r2 = sc[2], r3 = sc[3];
  if (op) {
    v.x = fmaxf(fmaxf(r0.x, r1.x), fmaxf(r2.x, r3.x));
    v.y = fmaxf(fmaxf(r0.y, r1.y), fmaxf(r2.y, r3.y));
    v.z = fmaxf(fmaxf(r0.z, r1.z), fmaxf(r2.z, r3.z));
    v.w = fmaxf(fmaxf(r0.w, r1.w), fmaxf(r2.w, r3.w));
  } else {
    v.x = r0.x + r1.x + r2.x + r3.x;
    v.y = r0.y + r1.y + r2.y + r3.y;
    v.z = r0.z + r1.z + r2.z + r3.z;
    v.w = r0.w + r1.w + r2.w + r3.w;
  }
  __syncthreads();
  return v;
}

// 64x64 @ 64x64 GEMM: A rows from TH (stride 72 u16), B cols from E2T (stride 72 u16).
__device__ __forceinline__ void gemm64(const unsigned short* TH, const unsigned short* E2T,
                                       int w, int l15, int quad, f32x4 acc[4][4]) {
#pragma unroll
  for (int tr = 0; tr < 4; ++tr)
#pragma unroll
    for (int tc = 0; tc < 4; ++tc)
      acc[tr][tc] = (f32x4){0.f, 0.f, 0.f, 0.f};
#pragma unroll
  for (int ms = 0; ms < 64; ms += 32) {
    bf16x8 af[4], bfr[4];
#pragma unroll
    for (int tr = 0; tr < 4; ++tr)
      af[tr] = *reinterpret_cast<const bf16x8*>(&TH[(64 * w + 16 * tr + l15) * 72 + ms + quad * 8]);
#pragma unroll
    for (int tc = 0; tc < 4; ++tc)
      bfr[tc] = *reinterpret_cast<const bf16x8*>(&E2T[(16 * tc + l15) * 72 + ms + quad * 8]);
#pragma unroll
    for (int tr = 0; tr < 4; ++tr)
#pragma unroll
      for (int tc = 0; tc < 4; ++tc)
        acc[tr][tc] = __builtin_amdgcn_mfma_f32_16x16x32_bf16(af[tr], bfr[tc], acc[tr][tc], 0, 0, 0);
  }
}

// Single fused kernel: one block per (b,i), 256 threads. LDS trimmed to ~51.8 KB
// via phase-ordered overlays -> 3 blocks/CU (12 waves/CU).
__global__ __launch_bounds__(256, 3) void k_all(
    const float* __restrict__ h, const float* __restrict__ x, const float* __restrict__ v,
    const float* __restrict__ ew1, const float* __restrict__ eb1,
    const float* __restrict__ ew2, const float* __restrict__ eb2,
    const float* __restrict__ semw, const float* __restrict__ semb,
    const float* __restrict__ pw1, const float* __restrict__ pb1,
    const float* __restrict__ pw2, const float* __restrict__ pb2,
    const float* __restrict__ nw1, const float* __restrict__ nb1,
    const float* __restrict__ nw2, const float* __restrict__ nb2,
    const float* __restrict__ vw1, const float* __restrict__ vb1,
    const float* __restrict__ vw2, const float* __restrict__ vmix,
    const float* __restrict__ lgam, float* __restrict__ out) {

  // TH: h_b(bf16) -> T -> HE ; after P4 reused as tail scratch.
  __shared__ __align__(16) unsigned short TH[256 * 72];   // 36864 B
  // E2u phases: E2T (W1a^T/W2^T/E3T, 9216 B) -> sd[256*8]f (0..8191) ->
  //             cat_l[256]f4 (0..4095) + cn_l (4096..) + hag_l (5120..) ; sc @8192, dvs @8320
  __shared__ __align__(16) char E2u[9216];
  __shared__ __align__(16) float4 unit_l[256];            // .xyz = unit, .w = dn
  __shared__ float addk[64];     // Bm_i[k] + eb1[k]
  __shared__ float w1dk[64];     // ew1 distance row
  __shared__ __align__(16) float bms[256];                // Bm partials (P0 only)

  unsigned short* E2T = (unsigned short*)E2u;
  float*  sd    = (float*)E2u;               // [256*8]
  float4* cat_l = (float4*)E2u;              // [256]
  float*  cn_l  = (float*)(E2u + 4096);      // [256]
  float*  hag_l = (float*)(E2u + 5120);      // [256]
  float4* sc    = (float4*)(E2u + 8192);     // [8]
  float*  dvs   = (float*)(E2u + 8320);      // [3]
  // tail scratch overlaid on TH (free after P4)
  float* tmp = (float*)TH;                   // [256]
  float* m1s = (float*)TH + 256;             // [64]
  float* hnw = (float*)TH + 320;             // [64]
  float* nin = (float*)TH + 384;             // [384]

  const int bi  = blockIdx.x;
  const int i   = bi & 255;
  const int b0  = bi & ~255;
  const int tid = threadIdx.x;
  const int j   = tid;
  const int bj  = b0 | j;

  // ================= P0: staging =================
  const float xi0 = x[bi * 3 + 0], xi1 = x[bi * 3 + 1], xi2 = x[bi * 3 + 2];
  const float dx = x[bj * 3 + 0] - xi0;
  const float dy = x[bj * 3 + 1] - xi1;
  const float dz = x[bj * 3 + 2] - xi2;
  const float dn = sqrtf(dx * dx + dy * dy + dz * dz + EPSV);
  const float invn = rcp_f(dn + EPSV);
  const float ux = dx * invn, uy = dy * invn, uz = dz * invn;
  unit_l[j] = make_float4(ux, uy, uz, dn);

  {
    const float4* hb4 = reinterpret_cast<const float4*>(h + (size_t)b0 * 64);
#pragma unroll
    for (int q = 0; q < 16; ++q) {
      int idx = q * 256 + tid;            // 0..4095 float4s
      float4 f4 = hb4[idx];
      int row = idx >> 4, c4 = idx & 15;
      uint2 pk;
      pk.x = pkbf(f4.x, f4.y);
      pk.y = pkbf(f4.z, f4.w);
      *reinterpret_cast<uint2*>(&TH[row * 72 + c4 * 4]) = pk;
    }
  }
  // stage W1a^T
#pragma unroll
  for (int q = 0; q < 16; ++q) {
    int idx = q * 256 + tid;              // f*64+k
    E2T[(idx & 63) * 72 + (idx >> 6)] = f2bf(ew1[idx]);
  }
  // Bm_i partials (fp32 exact)
  {
    int s = tid >> 6, k = tid & 63;
    const float* hrow = h + (size_t)bi * 64;      // uniform -> scalar loads
    float bp = 0.f;
#pragma unroll
    for (int f2 = 0; f2 < 16; ++f2) {
      int f = s * 16 + f2;
      bp += hrow[f] * ew1[(64 + f) * 64 + k];
    }
    bms[s * 64 + k] = bp;
  }
  __syncthreads();                                               // s1
  if (tid < 64) {
    addk[tid] = eb1[tid] + bms[tid] + bms[64 + tid] + bms[128 + tid] + bms[192 + tid];
    w1dk[tid] = ew1[128 * 64 + tid];
  }

  const int lid  = tid & 63;
  const int w    = tid >> 6;
  const int l15  = lid & 15;
  const int quad = lid >> 4;

  // ================= P1: GEMM1 (h_b @ W1a) =================
  f32x4 acc[4][4];
  gemm64(TH, E2T, w, l15, quad, acc);
  __syncthreads();                                               // s2

  // epilogue: T = silu(A + Bm_i + dn*w1d + eb1) -> TH
#pragma unroll
  for (int tc = 0; tc < 4; ++tc) {
    float ak = addk[16 * tc + l15];
    float wd = w1dk[16 * tc + l15];
#pragma unroll
    for (int tr = 0; tr < 4; ++tr)
#pragma unroll
      for (int r = 0; r < 4; ++r) {
        int row = 64 * w + 16 * tr + quad * 4 + r;
        float val = silu_f(acc[tr][tc][r] + ak + unit_l[row].w * wd);
        TH[row * 72 + 16 * tc + l15] = f2bf(val);
      }
  }
  // restage W2^T
#pragma unroll
  for (int q = 0; q < 16; ++q) {
    int idx = q * 256 + tid;
    E2T[(idx & 63) * 72 + (idx >> 6)] = f2bf(ew2[idx]);
  }
  __syncthreads();                                               // s3

  // ================= P2: GEMM2 (HE = T @ W2) =================
  gemm64(TH, E2T, w, l15, quad, acc);
  __syncthreads();                                               // s4

  // epilogue: HE = silu(. + eb2) -> TH ; stage E3T = [semw | vmix]^T (rows 0..7)
#pragma unroll
  for (int tc = 0; tc < 4; ++tc) {
    float b2 = eb2[16 * tc + l15];
#pragma unroll
    for (int tr = 0; tr < 4; ++tr)
#pragma unroll
      for (int r = 0; r < 4; ++r) {
        int row = 64 * w + 16 * tr + quad * 4 + r;
        TH[row * 72 + 16 * tc + l15] = f2bf(silu_f(acc[tr][tc][r] + b2));
      }
  }
#pragma unroll
  for (int q = 0; q < 2; ++q) {
    int idx = q * 256 + tid;          // n = idx>>6 (0..7), kk = idx&63
    int n = idx >> 6, kk = idx & 63;
    float wv = (n < 4) ? semw[kk * 4 + n] : vmix[kk * 4 + (n - 4)];
    E2T[n * 72 + kk] = f2bf(wv);
  }
  __syncthreads();                                               // s5

  // ================= P2b: GEMM3 (HE @ [semw|vmix]) =================
  f32x4 acc3[4];
  {
#pragma unroll
    for (int tr = 0; tr < 4; ++tr) acc3[tr] = (f32x4){0.f, 0.f, 0.f, 0.f};
#pragma unroll
    for (int ms = 0; ms < 64; ms += 32) {
      bf16x8 b3 = *reinterpret_cast<const bf16x8*>(&E2T[l15 * 72 + ms + quad * 8]);
#pragma unroll
      for (int tr = 0; tr < 4; ++tr) {
        bf16x8 a3 = *reinterpret_cast<const bf16x8*>(&TH[(64 * w + 16 * tr + l15) * 72 + ms + quad * 8]);
        acc3[tr] = __builtin_amdgcn_mfma_f32_16x16x32_bf16(a3, b3, acc3[tr], 0, 0, 0);
      }
    }
  }
  __syncthreads();                                               // s6: E2T reads done
  if (l15 < 8) {
#pragma unroll
    for (int tr = 0; tr < 4; ++tr)
#pragma unroll
      for (int r = 0; r < 4; ++r)
        sd[(64 * w + 16 * tr + quad * 4 + r) * 8 + l15] = acc3[tr][r];
  }
  __syncthreads();                                               // s7

  // ================= P3: attentions (thread = j) =================
  float4 s01 = *reinterpret_cast<const float4*>(sd + j * 8);       // sem logits (pre-bias)
  float4 s23 = *reinterpret_cast<const float4*>(sd + j * 8 + 4);   // vmix dots
  float4 sbv = *reinterpret_cast<const float4*>(semb);
  const float diag = (j == i) ? INFV : 0.0f;
  float4 sl;
  sl.x = s01.x + sbv.x; sl.y = s01.y + sbv.y; sl.z = s01.z + sbv.z; sl.w = s01.w + sbv.w;
  sl.x = ((sl.x > 0.f) ? sl.x : 0.2f * sl.x) - diag;
  sl.y = ((sl.y > 0.f) ? sl.y : 0.2f * sl.y) - diag;
  sl.z = ((sl.z > 0.f) ? sl.z : 0.2f * sl.z) - diag;
  sl.w = ((sl.w > 0.f) ? sl.w : 0.2f * sl.w) - diag;

  float4 lg = *reinterpret_cast<const float4*>(lgam);
  const float dni = dn + diag;
  // euclid logits <= 0: exp without max-subtraction safe (diag underflows to 0)
  float4 e_eu = make_float4(__expf(-dni * __expf(lg.x)), __expf(-dni * __expf(lg.y)),
                            __expf(-dni * __expf(lg.z)), __expf(-dni * __expf(lg.w)));

  float4 M = br4(sl, 1, sc);   // first sync here: all sd reads complete before cat_l writes
  float4 e_sem = make_float4(__expf(sl.x - M.x), __expf(sl.y - M.y),
                             __expf(sl.z - M.z), __expf(sl.w - M.w));

  // batched sums of e_eu and e_sem
  float4 a8 = e_eu, b8 = e_sem;
#pragma unroll
  for (int off = 32; off >= 1; off >>= 1) {
    a8.x += __shfl_xor(a8.x, off); a8.y += __shfl_xor(a8.y, off);
    a8.z += __shfl_xor(a8.z, off); a8.w += __shfl_xor(a8.w, off);
    b8.x += __shfl_xor(b8.x, off); b8.y += __shfl_xor(b8.y, off);
    b8.z += __shfl_xor(b8.z, off); b8.w += __shfl_xor(b8.w, off);
  }
  if ((tid & 63) == 0) { sc[tid >> 6] = a8; sc[4 + (tid >> 6)] = b8; }
  __syncthreads();
  float4 Se, Ss;
  {
    float4 r0 = sc[0], r1 = sc[1], r2 = sc[2], r3 = sc[3];
    Se = make_float4(r0.x + r1.x + r2.x + r3.x, r0.y + r1.y + r2.y + r3.y,
                     r0.z + r1.z + r2.z + r3.z, r0.w + r1.w + r2.w + r3.w);
    float4 s0 = sc[4], s1 = sc[5], s2 = sc[6], s3 = sc[7];
    Ss = make_float4(s0.x + s1.x + s2.x + s3.x, s0.y + s1.y + s2.y + s3.y,
                     s0.z + s1.z + s2.z + s3.z, s0.w + s1.w + s2.w + s3.w);
  }
  __syncthreads();

  float4 p = make_float4((e_eu.x * rcp_f(Se.x)) * (e_sem.x * rcp_f(Ss.x)),
                         (e_eu.y * rcp_f(Se.y)) * (e_sem.y * rcp_f(Ss.y)),
                         (e_eu.z * rcp_f(Se.z)) * (e_sem.z * rcp_f(Ss.z)),
                         (e_eu.w * rcp_f(Se.w)) * (e_sem.w * rcp_f(Ss.w)));
  float4 ep = make_float4(__expf(p.x), __expf(p.y), __expf(p.z), __expf(p.w));
  float4 Sp = br4(ep, 0, sc);
  float4 catt = make_float4(ep.x * rcp_f(Sp.x), ep.y * rcp_f(Sp.y),
                            ep.z * rcp_f(Sp.z), ep.w * rcp_f(Sp.w));
  cat_l[j] = catt;   // overlays sd (fully consumed)

  // delta_v: s_j = sum_hd catt[hd] * d[hd]
  float s = catt.x * s23.x + catt.y * s23.y + catt.z * s23.z + catt.w * s23.w;
  float4 dv = br4(make_float4(s * ux, s * uy, s * uz, 0.f), 0, sc);
  if (j == 0) {
    const float inv = 1.0f / 256.0f;
    dvs[0] = dv.x * inv; dvs[1] = dv.y * inv; dvs[2] = dv.z * inv;
  }
  // br4 ended with a sync: cat_l visible

  // ========== P4: comb_sum / h_agg, wave-local (wave w -> k in [16w,16w+16)) ==========
  {
    const int kk = lid & 15;
    const int jq = lid >> 4;
    const int k  = 16 * w + kk;
    float agg[4] = {0.f, 0.f, 0.f, 0.f};
    float ax[4]  = {0.f, 0.f, 0.f, 0.f};
    float ay[4]  = {0.f, 0.f, 0.f, 0.f};
    float az[4]  = {0.f, 0.f, 0.f, 0.f};
#pragma unroll 4
    for (int jr2 = 0; jr2 < 64; ++jr2) {
      int jj = jq * 64 + ((jr2 + 4 * jq) & 63);
      float hev = bf2f(TH[jj * 72 + k]);
      float4 ca = cat_l[jj];
      float4 u  = unit_l[jj];
      float w0 = hev * ca.x, w1 = hev * ca.y, w2 = hev * ca.z, w3 = hev * ca.w;
      agg[0] += w0; agg[1] += w1; agg[2] += w2; agg[3] += w3;
      ax[0] += w0 * u.x; ay[0] += w0 * u.y; az[0] += w0 * u.z;
      ax[1] += w1 * u.x; ay[1] += w1 * u.y; az[1] += w1 * u.z;
      ax[2] += w2 * u.x; ay[2] += w2 * u.y; az[2] += w2 * u.z;
      ax[3] += w3 * u.x; ay[3] += w3 * u.y; az[3] += w3 * u.z;
    }
#pragma unroll
    for (int off = 16; off <= 32; off <<= 1) {
#pragma unroll
      for (int hd = 0; hd < 4; ++hd) {
        agg[hd] += __shfl_xor(agg[hd], off);
        ax[hd]  += __shfl_xor(ax[hd], off);
        ay[hd]  += __shfl_xor(ay[hd], off);
        az[hd]  += __shfl_xor(az[hd], off);
      }
    }
    if (jq == 0) {
      const float inv = 1.0f / 256.0f;
#pragma unroll
      for (int hd = 0; hd < 4; ++hd) {
        float cx = ax[hd] * inv, cy = ay[hd] * inv, cz = az[hd] * inv;
        cn_l[k * 4 + hd]  = cx * cx + cy * cy + cz * cz;
        hag_l[k * 4 + hd] = agg[hd];
      }
    }
  }
  __syncthreads();                                               // s8: TH free, cn/hag ready

  // ================= P5: tail MLPs, strip-parallel (wave = strip) =================
  const int k = tid & 63;
  // post1: 256 -> 64
  {
    float a = 0.f;
    for (int m2 = 0; m2 < 64; ++m2) {
      int m = w * 64 + m2;
      a += cn_l[m] * pw1[m * 64 + k];
    }
    tmp[tid] = a;
  }
  __syncthreads();
  if (tid < 64) m1s[tid] = silu_f(pb1[tid] + tmp[tid] + tmp[64 + tid] + tmp[128 + tid] + tmp[192 + tid]);
  __syncthreads();
  // post2: 64 -> 64 ; stage h_agg into nin
  {
    float a = 0.f;
#pragma unroll
    for (int m2 = 0; m2 < 16; ++m2) {
      int m = w * 16 + m2;
      a += m1s[m] * pw2[m * 64 + k];
    }
    float hgv = hag_l[tid];
    __syncthreads();            // m1s reads done; tmp (TH) writes below race-free vs P5 reads
    tmp[tid] = a;
    nin[64 + tid] = hgv;
  }
  __syncthreads();
  if (tid < 64) {
    nin[tid] = h[(size_t)bi * 64 + tid];
    nin[320 + tid] = silu_f(pb2[tid] + tmp[tid] + tmp[64 + tid] + tmp[128 + tid] + tmp[192 + tid]);
  }
  __syncthreads();
  // node1: 384 -> 64
  {
    float a = 0.f;
    for (int m2 = 0; m2 < 96; ++m2) {
      int m = w * 96 + m2;
      a += nin[m] * nw1[m * 64 + k];
    }
    __syncthreads();
    tmp[tid] = a;
  }
  __syncthreads();
  if (tid < 64) m1s[tid] = silu_f(nb1[tid] + tmp[tid] + tmp[64 + tid] + tmp[128 + tid] + tmp[192 + tid]);
  __syncthreads();
  // node2: 64 -> 64, residual
  {
    float a = 0.f;
#pragma unroll
    for (int m2 = 0; m2 < 16; ++m2) {
      int m = w * 16 + m2;
      a += m1s[m] * nw2[m * 64 + k];
    }
    __syncthreads();
    tmp[tid] = a;
  }
  __syncthreads();
  if (tid < 64) {
    float hn = h[(size_t)bi * 64 + tid] +
               silu_f(nb2[tid] + tmp[tid] + tmp[64 + tid] + tmp[128 + tid] + tmp[192 + tid]);
    out[(size_t)bi * 64 + tid] = hn;
    hnw[tid] = hn;
  }
  __syncthreads();
  // vel: 64 -> 64 -> scalar, then x/v outputs
  {
    float a = 0.f;
#pragma unroll
    for (int m2 = 0; m2 < 16; ++m2) {
      int m = w * 16 + m2;
      a += hnw[m] * vw1[m * 64 + k];
    }
    __syncthreads();
    tmp[tid] = a;
  }
  __syncthreads();
  if (tid < 64) {
    float vh = silu_f(vb1[tid] + tmp[tid] + tmp[64 + tid] + tmp[128 + tid] + tmp[192 + tid]) * vw2[tid];
#pragma unroll
    for (int off = 32; off >= 1; off >>= 1) vh += __shfl_xor(vh, off);
    if (tid == 0) {
#pragma unroll
      for (int d = 0; d < 3; ++d) {
        float vn = dvs[d] + vh * v[bi * 3 + d];
        out[32768 + bi * 3 + d] = x[bi * 3 + d] + vn;
        out[34304 + bi * 3 + d] = vn;
      }
    }
  }
}

extern "C" void kernel_launch(void* const* d_in, const int* in_sizes, int n_in,
                              void* d_out, int out_size, void* d_ws, size_t ws_size,
                              hipStream_t stream) {
  const float* h    = (const float*)d_in[0];
  const float* x    = (const float*)d_in[1];
  const float* v    = (const float*)d_in[2];
  const float* ew1  = (const float*)d_in[3];
  const float* eb1  = (const float*)d_in[4];
  const float* ew2  = (const float*)d_in[5];
  const float* eb2  = (const float*)d_in[6];
  const float* semw = (const float*)d_in[7];
  const float* semb = (const float*)d_in[8];
  const float* pw1  = (const float*)d_in[9];
  const float* pb1  = (const float*)d_in[10];
  const float* pw2  = (const float*)d_in[11];
  const float* pb2  = (const float*)d_in[12];
  const float* nw1  = (const float*)d_in[13];
  const float* nb1  = (const float*)d_in[14];
  const float* nw2  = (const float*)d_in[15];
  const float* nb2  = (const float*)d_in[16];
  const float* vw1  = (const float*)d_in[17];
  const float* vb1  = (const float*)d_in[18];
  const float* vw2  = (const float*)d_in[19];
  const float* vmix = (const float*)d_in[20];
  const float* lgam = (const float*)d_in[21];
  float* out = (float*)d_out;

  k_all<<<512, 256, 0, stream>>>(h, x, v, ew1, eb1, ew2, eb2, semw, semb,
                                 pw1, pb1, pw2, pb2, nw1, nb1, nw2, nb2,
                                 vw1, vb1, vw2, vmix, lgam, out);
}